// Round 6
// baseline (235.931 us; speedup 1.0000x reference)
//
#include <hip/hip_runtime.h>
#include <hip/hip_bf16.h>

// Music-Transformer RelativeGlobalAttention, MI355X round 13.
// B=2, T=2048, D=512, H=8, hd=64, ED=512, EV=388. fp32 I/O (runtime-detected
// via mask[0] bit pattern), bf16 MFMA compute, fp32 accumulation.
// R13: occupancy attack via LDS diet (Common-mistake #7: don't LDS-stage
// L2-fitting data). K+V per hb = 512KB, L2-resident with the XCD-local block
// map -> read K/V frags DIRECT from global (L2 ~200cyc, hidden by TLP).
// LDS = sE (32KB, DMA double-buffered -- dedup still essential: direct E was
// 70% of traffic in R9) + sP (8KB) = 40KB -> 4 blocks/CU = 16 waves/CU
// (2x R12's TLP). Per-step DMA 8->4 instrs; grid 1008 (R9 63-chunk table)
// now ONE resident cohort (<=1024). launch_bounds(256,4) caps VGPR at 128.

#define B_ 2
#define T_ 2048
#define DM_ 512
#define H_ 8
#define HD_ 64
#define ED_ 512
#define EV_ 388
#define BT_ (B_ * T_)

typedef __attribute__((ext_vector_type(8))) short short8;
typedef __attribute__((ext_vector_type(4))) float floatx4;

#define MFMA(a, b, c) __builtin_amdgcn_mfma_f32_16x16x32_bf16((a), (b), (c), 0, 0, 0)

__device__ __forceinline__ float bfs(unsigned short s) {
  union { unsigned int i; float f; } v; v.i = ((unsigned int)s) << 16; return v.f;
}
__device__ __forceinline__ unsigned short f2bf(float f) {
  __hip_bfloat16 h = __float2bfloat16(f);
  union { __hip_bfloat16 h; unsigned short u; } v; v.h = h; return v.u;
}
__device__ __forceinline__ float ldf(const void* p, int i, bool isbf) {
  return isbf ? bfs(((const unsigned short*)p)[i]) : ((const float*)p)[i];
}
__device__ __forceinline__ bool det_bf(const unsigned int* mask) {
  return mask[0] != 0x3F800000u;  // fp32 1.0f word; bf16-packed differs
}
__device__ __forceinline__ void gl_lds16(const unsigned short* g, void* l) {
  __builtin_amdgcn_global_load_lds(
      (const __attribute__((address_space(1))) void*)g,
      (__attribute__((address_space(3))) void*)l, 16, 0, 0);
}

// ---------------------------------------------------------------------------
// K0 prep: [0,1024) E->bf16 copy/convert; [1024,1312) weight transposes
// src [512][N] -> dst [Npad][512] bf16, zero-padded rows.
// ---------------------------------------------------------------------------
__global__ __launch_bounds__(256) void prep_kernel(
    const void* __restrict__ E, const void* __restrict__ Wq,
    const void* __restrict__ Wk, const void* __restrict__ Wv,
    const void* __restrict__ Wo, const void* __restrict__ Wl,
    const unsigned int* __restrict__ mask,
    unsigned short* __restrict__ E_c, unsigned short* __restrict__ WqT,
    unsigned short* __restrict__ WkT, unsigned short* __restrict__ WvT,
    unsigned short* __restrict__ WoT, unsigned short* __restrict__ WlT) {
  const bool isbf = det_bf(mask);
  const int tid = threadIdx.x;
  int bi = blockIdx.x;
  if (bi < 1024) {
    const int i0 = (bi * 256 + tid) * 4;
    if (isbf) {
      *(uint2*)&E_c[i0] = *(const uint2*)((const unsigned short*)E + i0);
    } else {
      float4 f = *(const float4*)((const float*)E + i0);
      unsigned short p[4] = {f2bf(f.x), f2bf(f.y), f2bf(f.z), f2bf(f.w)};
      *(uint2*)&E_c[i0] = *(uint2*)p;
    }
    return;
  }
  bi -= 1024;
  const void* src; unsigned short* dst; int N, nb;
  if (bi < 16)       { src = Wq; dst = WqT; N = 64;  nb = bi; }
  else if (bi < 32)  { src = Wk; dst = WkT; N = 64;  nb = bi - 16; }
  else if (bi < 48)  { src = Wv; dst = WvT; N = 64;  nb = bi - 32; }
  else if (bi < 176) { src = Wo; dst = WoT; N = 512; nb = bi - 48; }
  else               { src = Wl; dst = WlT; N = 388; nb = bi - 176; }
  const int n = nb * 4 + (tid >> 6);
  const int k0 = (tid & 63) * 8;
  unsigned short vv[8];
#pragma unroll
  for (int j = 0; j < 8; ++j) {
    if (n >= N) vv[j] = 0;
    else if (isbf) vv[j] = ((const unsigned short*)src)[(size_t)(k0 + j) * N + n];
    else vv[j] = f2bf(((const float*)src)[(size_t)(k0 + j) * N + n]);
  }
  *(uint4*)&dst[(size_t)n * DM_ + k0] = *(uint4*)vv;
}

// ---------------------------------------------------------------------------
// K1: projections. grid (64, 3), tile 64x64, block 256 (4 waves).
// sel 0/1 -> qh/kh row-major bf16 [4096][64]; sel 2 -> vt [B][64][2048] bf16.
// ---------------------------------------------------------------------------
__global__ __launch_bounds__(256) void gemm_proj(
    const void* __restrict__ xq, const void* __restrict__ xk,
    const void* __restrict__ xv,
    const unsigned short* __restrict__ WqT, const unsigned short* __restrict__ WkT,
    const unsigned short* __restrict__ WvT,
    const void* __restrict__ bq, const void* __restrict__ bk,
    const void* __restrict__ bv, const unsigned int* __restrict__ mask,
    unsigned short* __restrict__ oq, unsigned short* __restrict__ ok,
    unsigned short* __restrict__ ovt) {
  __shared__ __align__(16) short sA[64][72];
  __shared__ __align__(16) short sW[64][72];
  const int sel = blockIdx.y;
  const void* x = (sel == 0) ? xq : (sel == 1) ? xk : xv;
  const unsigned short* WT = (sel == 0) ? WqT : (sel == 1) ? WkT : WvT;
  const void* bias = (sel == 0) ? bq : (sel == 1) ? bk : bv;
  const bool isbf = det_bf(mask);

  const int tid = threadIdx.x;
  const int w = tid >> 6, lane = tid & 63;
  const int q_ = lane >> 4, n_ = lane & 15;
  const int row0 = blockIdx.x * 64;

  floatx4 acc[4];
#pragma unroll
  for (int j = 0; j < 4; ++j) acc[j] = (floatx4){0.f, 0.f, 0.f, 0.f};

  for (int k0 = 0; k0 < DM_; k0 += 64) {
    if (isbf) {
#pragma unroll
      for (int it = 0; it < 2; ++it) {
        int idx = tid + it * 256;
        int rr = idx >> 3, cc = (idx & 7) * 8;
        *(uint4*)&sA[rr][cc] =
            *(const uint4*)((const unsigned short*)x + (size_t)(row0 + rr) * DM_ + k0 + cc);
      }
    } else {
#pragma unroll
      for (int it = 0; it < 4; ++it) {
        int idx = tid + it * 256;
        int rr = idx >> 4, cc = (idx & 15) * 4;
        float4 f = *(const float4*)((const float*)x + (size_t)(row0 + rr) * DM_ + k0 + cc);
        unsigned short p[4] = {f2bf(f.x), f2bf(f.y), f2bf(f.z), f2bf(f.w)};
        *(uint2*)&sA[rr][cc] = *(uint2*)p;
      }
    }
#pragma unroll
    for (int it = 0; it < 2; ++it) {
      int idx = tid + it * 256;
      int rr = idx >> 3, cc = (idx & 7) * 8;
      *(uint4*)&sW[rr][cc] = *(const uint4*)(WT + (size_t)rr * DM_ + k0 + cc);
    }
    __syncthreads();
    short8 a0 = *(const short8*)&sA[16 * w + n_][8 * q_];
    short8 a1 = *(const short8*)&sA[16 * w + n_][32 + 8 * q_];
#pragma unroll
    for (int nb = 0; nb < 4; ++nb) {
      short8 b0 = *(const short8*)&sW[16 * nb + n_][8 * q_];
      short8 b1 = *(const short8*)&sW[16 * nb + n_][32 + 8 * q_];
      acc[nb] = MFMA(a0, b0, acc[nb]);
      acc[nb] = MFMA(a1, b1, acc[nb]);
    }
    __syncthreads();
  }

#pragma unroll
  for (int nb = 0; nb < 4; ++nb) {
    const int col = 16 * nb + n_;
    const float bb = ldf(bias, col, isbf);
#pragma unroll
    for (int r = 0; r < 4; ++r) {
      int row = row0 + 16 * w + 4 * q_ + r;
      unsigned short val = f2bf(acc[nb][r] + bb);
      if (sel < 2) {
        unsigned short* o = (sel == 0) ? oq : ok;
        o[(size_t)row * HD_ + col] = val;
      } else {
        int b = row >> 11, s = row & 2047;
        ovt[(((size_t)(b * HD_ + col)) << 11) + s] = val;
      }
    }
  }
}

// ---------------------------------------------------------------------------
// Chunk mapping (R13 = R9 table): 63 chunks/hb, grid 1008; hb = id & 15
// (all chunks of an hb share id%8 -> same XCD), rem = id >> 4.
// ti 0..10 -> 1 chunk; 11..21 -> 2; 22..31 -> 3. Max 11 K-steps/chunk.
// Multi-chunk tiles store partials at slot hb*52 + pbase(ti) + c.
// ---------------------------------------------------------------------------
__device__ __forceinline__ int pbase_of(int ti) {
  return (ti < 22) ? (ti - 11) * 2 : 22 + (ti - 22) * 3;
}

// ---------------------------------------------------------------------------
// K2: fused causal attention. grid 1008 (one resident cohort at 4 blocks/CU).
// 4 waves/block, each a 16-row q-strip. K/V frags read DIRECT from global
// (L2-resident); only the 128-row E window is DMA-staged (double-buffered,
// pre-swizzled source); one raw s_barrier + vmcnt(0) per step. No running
// max; l via all-ones MFMA; P in per-wave swizzled LDS strip.
// ---------------------------------------------------------------------------
__global__ __launch_bounds__(256, 4) void attn_kernel(
    const unsigned short* __restrict__ qh, const unsigned short* __restrict__ kh,
    const unsigned short* __restrict__ vt, const unsigned short* __restrict__ E,
    unsigned short* __restrict__ ctxo, float* __restrict__ pc,
    float* __restrict__ ml) {
  __shared__ __align__(16) short sE[2][128][64];   // 32 KB
  __shared__ __align__(16) short sP[64][64];       // 8 KB; wave w rows [16w,16w+16)

  const int id = blockIdx.x;
  const int hb = id & 15;    // all chunks of hb share id%8 -> same XCD
  const int rem = id >> 4;   // chunk index 0..62
  int ti, c, nc;
  if (rem < 11)      { ti = rem;                  c = 0;              nc = 1; }
  else if (rem < 33) { ti = 11 + ((rem - 11) >> 1); c = (rem - 11) & 1; nc = 2; }
  else               { ti = 22 + (rem - 33) / 3;    c = (rem - 33) % 3; nc = 3; }
  const int nsteps = ti + 1;
  const int klo = (c * nsteps) / nc;
  const int khi = ((c + 1) * nsteps) / nc;

  const int h = hb >> 1, b = hb & 1;
  const int t0 = ti * 64;

  const int tid = threadIdx.x;
  const int w = tid >> 6, lane = tid & 63;
  const int q_ = lane >> 4, n_ = lane & 15;

  const int trow = t0 + 16 * w + n_;
  const unsigned short* qp = qh + (((size_t)((b << 11) + trow)) << 6) + (q_ << 3);
  const short8 qa0 = *(const short8*)qp;
  const short8 qa1 = *(const short8*)(qp + 32);

  short8 onesf;
#pragma unroll
  for (int j = 0; j < 8; ++j) onesf[j] = (short)0x3F80;  // bf16 1.0

  floatx4 ctxa[4];
#pragma unroll
  for (int nb = 0; nb < 4; ++nb) ctxa[nb] = (floatx4){0.f, 0.f, 0.f, 0.f};
  floatx4 lacc = (floatx4){0.f, 0.f, 0.f, 0.f};

  const unsigned short* eb = E + ((size_t)h << 17);
  // Direct-frag bases: lane reads K row (s0+16nb+n_), col-chunk q_ and q_+4;
  // V row (d=16nb+n_), col s0+8q_ / +32.
  const unsigned short* kfr = kh + (((size_t)(b << 11) + n_) << 6) + (q_ << 3);
  const unsigned short* vfr = vt + (((size_t)((b << 6) + n_)) << 11) + (q_ << 3);

  // E DMA staging geometry (pre-swizzled source, linear LDS dest):
  const int lrow8 = lane >> 3;                     // 0..7
  const int lch = ((lane & 7) ^ lrow8) << 3;       // swizzled source col
  // Swizzled read cols (logical chunk q_ / q_+4 of a row with row%8 == n_&7):
  const int c0s = ((q_ ^ (n_ & 7)) << 3);
  const int c1s = (((q_ | 4) ^ (n_ & 7)) << 3);

#define STAGE(bufsel, s0v)                                                     \
  {                                                                            \
    const int rbE = (T_ - 64) + (s0v)-t0;                                      \
    _Pragma("unroll") for (int off = 0; off < 4; ++off) {                      \
      int gr = rbE + 32 * w + 8 * off + lrow8;                                 \
      if (gr > T_ - 1) gr = T_ - 1; /* clamped rows are masked s>t */          \
      gl_lds16(eb + ((size_t)gr << 6) + lch,                                   \
               (void*)&sE[bufsel][32 * w + 8 * off][0]);                       \
    }                                                                          \
  }

  // Prologue: stage first E window (naked latency, once per block).
  STAGE(0, klo * 64);

  for (int kt = klo; kt < khi; ++kt) {
    const int cur = (kt - klo) & 1;
    const int s0 = kt * 64;

    // Own E DMA for this step complete -> publish to all waves.
    asm volatile("s_waitcnt vmcnt(0)" ::: "memory");
    __builtin_amdgcn_sched_barrier(0);
    __builtin_amdgcn_s_barrier();
    __builtin_amdgcn_sched_barrier(0);

    // Issue next window's DMA (lands during this step's compute).
    if (kt + 1 < khi) STAGE(cur ^ 1, s0 + 64);

    // ---- QK MFMA, K frags direct from global (L2-hit) ----
    floatx4 qk[4];
    __builtin_amdgcn_s_setprio(1);
#pragma unroll
    for (int nb = 0; nb < 4; ++nb) {
      const unsigned short* kp = kfr + (((size_t)(s0 + 16 * nb)) << 6);
      short8 kb0 = *(const short8*)kp;
      short8 kb1 = *(const short8*)(kp + 32);
      qk[nb] = (floatx4){0.f, 0.f, 0.f, 0.f};
      qk[nb] = MFMA(qa0, kb0, qk[nb]);
      qk[nb] = MFMA(qa1, kb1, qk[nb]);
    }
    // ---- QE MFMA from LDS E window (staged last step) ----
    floatx4 qe[5];
#pragma unroll
    for (int f = 0; f < 5; ++f) {
      const short* ep = &sE[cur][16 * (3 - w + f) + n_][0];
      short8 eb0 = *(const short8*)(ep + c0s);
      short8 eb1 = *(const short8*)(ep + c1s);
      qe[f] = (floatx4){0.f, 0.f, 0.f, 0.f};
      qe[f] = MFMA(qa0, eb0, qe[f]);
      qe[f] = MFMA(qa1, eb1, qe[f]);
    }
    __builtin_amdgcn_s_setprio(0);

    // ---- skew diagonal (16 bpermute, source-side frag select) + exp + sP --
    const bool diag = (kt == ti);
#pragma unroll
    for (int r = 0; r < 4; ++r) {
      const int t = 4 * q_ + r;
      const int ba = ((q_ << 4) | ((n_ - t + 15) & 15)) << 2;
      const int nd = (n_ + t + 1) & 15;   // dest lane (same q_) pulling from us
      const bool hi = nd > t;             // dest picks qe[mb+1] iff its n_ > t
      const int swr = (t & 7) << 3;       // sP row-swizzle term
#pragma unroll
      for (int mb = 0; mb < 4; ++mb) {
        float merged = hi ? qe[mb + 1][r] : qe[mb][r];
        float g = __int_as_float(
            __builtin_amdgcn_ds_bpermute(ba, __float_as_int(merged)));
        float sv = qk[mb][r] + g;
        if (diag && (16 * mb + n_ > 16 * w + t)) sv = -1.0e30f;  // exp -> 0
        // exp(sv*0.125) == exp2(sv * 0.125*log2(e))
        sP[16 * w + t][(16 * mb + n_) ^ swr] =
            (short)f2bf(exp2f(sv * 0.18033688011f));
      }
    }

    // ---- PV + l MFMA; V frags direct from global (L2-hit) ----
    short8 pa0 = *(const short8*)&sP[16 * w + n_][c0s];
    short8 pa1 = *(const short8*)&sP[16 * w + n_][c1s];
    __builtin_amdgcn_s_setprio(1);
#pragma unroll
    for (int nb = 0; nb < 4; ++nb) {
      const unsigned short* vp = vfr + (((size_t)(16 * nb)) << 11) + s0;
      short8 v0 = *(const short8*)vp;
      short8 v1 = *(const short8*)(vp + 32);
      ctxa[nb] = MFMA(pa0, v0, ctxa[nb]);
      ctxa[nb] = MFMA(pa1, v1, ctxa[nb]);
    }
    lacc = MFMA(pa0, onesf, lacc);
    lacc = MFMA(pa1, onesf, lacc);
    __builtin_amdgcn_s_setprio(0);
  }
#undef STAGE

  if (nc == 1) {
#pragma unroll
    for (int r = 0; r < 4; ++r) {
      const float inv = 1.0f / lacc[r];
      const int row = t0 + 16 * w + 4 * q_ + r;
      const size_t base = (((size_t)((b << 11) + row)) << 9) + (h << 6) + n_;
#pragma unroll
      for (int nb = 0; nb < 4; ++nb)
        ctxo[base + 16 * nb] = f2bf(ctxa[nb][r] * inv);
    }
  } else {
    const int idx = hb * 52 + pbase_of(ti) + c;
    float* pcb = pc + ((size_t)idx << 12);   // *4096
    float* mlb = ml + ((size_t)idx << 6);    // *64
#pragma unroll
    for (int r = 0; r < 4; ++r) {
      const int row = 16 * w + 4 * q_ + r;
#pragma unroll
      for (int nb = 0; nb < 4; ++nb)
        pcb[(row << 6) + 16 * nb + n_] = ctxa[nb][r];
      if (n_ == 0) mlb[row] = lacc[r];
    }
  }
}

// ---------------------------------------------------------------------------
// K2b: combine chunk partials: out = sum(c_i) / sum(l_i). grid 336 blocks
// (16 hb x 21 multi-chunk tiles, ti 11..31).
// ---------------------------------------------------------------------------
__global__ __launch_bounds__(256) void combine_kernel(
    const float* __restrict__ pc, const float* __restrict__ ml,
    unsigned short* __restrict__ ctxo) {
  const int cb = blockIdx.x;
  const int hb = cb / 21;
  const int ti = 11 + cb % 21;
  const int nc = (ti < 22) ? 2 : 3;
  const int h = hb >> 1, b = hb & 1, t0 = ti * 64;
  const int tid = threadIdx.x;
  const int row = tid >> 2, seg = (tid & 3) * 16;
  const int idx0 = hb * 52 + pbase_of(ti);

  float lsum = 0.f;
  float4 a4[4];
#pragma unroll
  for (int j = 0; j < 4; ++j) a4[j] = (float4){0.f, 0.f, 0.f, 0.f};
  for (int c = 0; c < nc; ++c) {
    const int idx = idx0 + c;
    lsum += ml[((size_t)idx << 6) + row];
    const float* cp = pc + ((size_t)idx << 12) + (row << 6) + seg;
#pragma unroll
    for (int j = 0; j < 4; ++j) {
      float4 x = *(const float4*)(cp + 4 * j);
      a4[j].x += x.x; a4[j].y += x.y; a4[j].z += x.z; a4[j].w += x.w;
    }
  }
  const float inv = 1.0f / lsum;
  unsigned short o[16];
#pragma unroll
  for (int j = 0; j < 4; ++j) {
    o[4 * j + 0] = f2bf(a4[j].x * inv);
    o[4 * j + 1] = f2bf(a4[j].y * inv);
    o[4 * j + 2] = f2bf(a4[j].z * inv);
    o[4 * j + 3] = f2bf(a4[j].w * inv);
  }
  unsigned short* dst =
      ctxo + (((size_t)((b << 11) + t0 + row)) << 9) + (h << 6) + seg;
  *(uint4*)dst = *(uint4*)&o[0];
  *(uint4*)(dst + 8) = *(uint4*)&o[8];
}

// ---------------------------------------------------------------------------
// K3: MFMA GEMM, A bf16 [4096][512] @ WT bf16 [Npad][512] + bias, tile 64x64.
// RELU=1: out h1 bf16 [4096][512]. RELU=0: out d_out (dtype per mask), N=388.
// ---------------------------------------------------------------------------
template <int RELU>
__global__ __launch_bounds__(256) void mlp_mfma(
    const unsigned short* __restrict__ A, const unsigned short* __restrict__ WT,
    const void* __restrict__ bias, unsigned short* __restrict__ outBF,
    void* __restrict__ outD, const unsigned int* __restrict__ mask) {
  __shared__ __align__(16) short sA[64][72];
  __shared__ __align__(16) short sW[64][72];
  const int tid = threadIdx.x;
  const int w = tid >> 6, lane = tid & 63;
  const int q_ = lane >> 4, n_ = lane & 15;
  const int row0 = blockIdx.x * 64;
  const int n0 = blockIdx.y * 64;
  const bool isbf = det_bf(mask);

  floatx4 acc[4];
#pragma unroll
  for (int j = 0; j < 4; ++j) acc[j] = (floatx4){0.f, 0.f, 0.f, 0.f};

  for (int k0 = 0; k0 < DM_; k0 += 64) {
#pragma unroll
    for (int it = 0; it < 2; ++it) {
      int idx = tid + it * 256;
      int rr = idx >> 3, cc = (idx & 7) * 8;
      *(uint4*)&sA[rr][cc] = *(const uint4*)(A + (size_t)(row0 + rr) * DM_ + k0 + cc);
      *(uint4*)&sW[rr][cc] = *(const uint4*)(WT + (size_t)(n0 + rr) * DM_ + k0 + cc);
    }
    __syncthreads();
    short8 a0 = *(const short8*)&sA[16 * w + n_][8 * q_];
    short8 a1 = *(const short8*)&sA[16 * w + n_][32 + 8 * q_];
#pragma unroll
    for (int nb = 0; nb < 4; ++nb) {
      short8 b0 = *(const short8*)&sW[16 * nb + n_][8 * q_];
      short8 b1 = *(const short8*)&sW[16 * nb + n_][32 + 8 * q_];
      acc[nb] = MFMA(a0, b0, acc[nb]);
      acc[nb] = MFMA(a1, b1, acc[nb]);
    }
    __syncthreads();
  }

#pragma unroll
  for (int nb = 0; nb < 4; ++nb) {
    const int col = n0 + 16 * nb + n_;
    float bb = 0.f;
    if (RELU || col < EV_) bb = ldf(bias, col, isbf);
#pragma unroll
    for (int r = 0; r < 4; ++r) {
      const int row = row0 + 16 * w + 4 * q_ + r;
      float v = acc[nb][r] + bb;
      if (RELU) {
        outBF[(size_t)row * ED_ + col] = f2bf(fmaxf(v, 0.f));
      } else if (col < EV_) {
        if (isbf) ((unsigned short*)outD)[(size_t)row * EV_ + col] = f2bf(v);
        else      ((float*)outD)[(size_t)row * EV_ + col] = v;
      }
    }
  }
}

// ---------------------------------------------------------------------------
extern "C" void kernel_launch(void* const* d_in, const int* in_sizes, int n_in,
                              void* d_out, int out_size, void* d_ws, size_t ws_size,
                              hipStream_t stream) {
  const void* v  = d_in[0];
  const void* k  = d_in[1];
  const void* q  = d_in[2];
  const unsigned int* mask = (const unsigned int*)d_in[3];
  const void* Wq = d_in[4];
  const void* bq = d_in[5];
  const void* Wk = d_in[6];
  const void* bk = d_in[7];
  const void* Wv = d_in[8];
  const void* bv = d_in[9];
  const void* E  = d_in[10];
  const void* Wo = d_in[11];
  const void* bo = d_in[12];
  const void* Wl = d_in[13];
  const void* bl = d_in[14];

  char* p = (char*)d_ws;
  unsigned short* E_c  = (unsigned short*)p; p += (size_t)H_ * T_ * HD_ * 2;  // 2 MB
  unsigned short* qhb  = (unsigned short*)p; p += (size_t)BT_ * HD_ * 2;
  unsigned short* khb  = (unsigned short*)p; p += (size_t)BT_ * HD_ * 2;
  unsigned short* vtb  = (unsigned short*)p; p += (size_t)BT_ * HD_ * 2;
  unsigned short* WqT  = (unsigned short*)p; p += (size_t)HD_ * DM_ * 2;
  unsigned short* WkT  = (unsigned short*)p; p += (size_t)HD_ * DM_ * 2;
  unsigned short* WvT  = (unsigned short*)p; p += (size_t)HD_ * DM_ * 2;
  unsigned short* WoT  = (unsigned short*)p; p += (size_t)ED_ * DM_ * 2;
  unsigned short* WlT  = (unsigned short*)p; p += (size_t)448 * DM_ * 2;
  unsigned short* ctxb = (unsigned short*)p; p += (size_t)BT_ * DM_ * 2;      // 4 MB
  unsigned short* h1b  = (unsigned short*)p; p += (size_t)BT_ * ED_ * 2;      // 4 MB
  float* pc = (float*)p; p += (size_t)16 * 52 * 4096 * 4;                     // 13.6 MB
  float* ml = (float*)p; p += (size_t)16 * 52 * 64 * 4;                       // 0.2 MB

  prep_kernel<<<dim3(1312), 256, 0, stream>>>(
      E, Wq, Wk, Wv, Wo, Wl, mask, E_c, WqT, WkT, WvT, WoT, WlT);
  gemm_proj<<<dim3(BT_ / 64, 3), 256, 0, stream>>>(
      q, k, v, WqT, WkT, WvT, bq, bk, bv, mask, qhb, khb, vtb);
  attn_kernel<<<dim3(1008), 256, 0, stream>>>(qhb, khb, vtb, E_c, ctxb, pc, ml);
  combine_kernel<<<dim3(336), 256, 0, stream>>>(pc, ml, ctxb);
  mlp_mfma<1><<<dim3(BT_ / 64, ED_ / 64), 256, 0, stream>>>(
      ctxb, WoT, bo, h1b, nullptr, mask);
  mlp_mfma<0><<<dim3(BT_ / 64, 448 / 64), 256, 0, stream>>>(
      h1b, WlT, bl, nullptr, d_out, mask);
}

// Round 8
// 206.674 us; speedup vs baseline: 1.1416x; 1.1416x over previous
//
#include <hip/hip_runtime.h>
#include <hip/hip_bf16.h>

// Music-Transformer RelativeGlobalAttention, MI355X round 15 (= R14 resubmit).
// B=2, T=2048, D=512, H=8, hd=64, ED=512, EV=388. fp32 I/O (runtime-detected
// via mask[0] bit pattern), bf16 MFMA compute, fp32 accumulation.
// R14/15 = R12 (best, 59us attn: K/V/E all DMA-staged, zero in-step vmem) +
// DEFERRED PV (T15 pattern): PV of step kt runs in step kt+1, where it is
// independent of that step's QK/QE and fills their ds_read/MFMA latency
// shadow; the exp->sP->PV serialization leaves the per-step critical path.
// pa-fragments carried in regs across the barrier (zero-init hardening);
// V ring-buffer sVT[3] (PV(kt-1) reads vprev while DMA fills vnext; mod-3
// all distinct, barrier separates cross-wave STAGE writes from reads).
// LDS 72->80KB, still 2 blocks/CU. R7's bench run died with a container
// acquisition error (no kernel diagnostic) -- resubmitting for measurement.

#define B_ 2
#define T_ 2048
#define DM_ 512
#define H_ 8
#define HD_ 64
#define ED_ 512
#define EV_ 388
#define BT_ (B_ * T_)

typedef __attribute__((ext_vector_type(8))) short short8;
typedef __attribute__((ext_vector_type(4))) float floatx4;

#define MFMA(a, b, c) __builtin_amdgcn_mfma_f32_16x16x32_bf16((a), (b), (c), 0, 0, 0)

__device__ __forceinline__ float bfs(unsigned short s) {
  union { unsigned int i; float f; } v; v.i = ((unsigned int)s) << 16; return v.f;
}
__device__ __forceinline__ unsigned short f2bf(float f) {
  __hip_bfloat16 h = __float2bfloat16(f);
  union { __hip_bfloat16 h; unsigned short u; } v; v.h = h; return v.u;
}
__device__ __forceinline__ float ldf(const void* p, int i, bool isbf) {
  return isbf ? bfs(((const unsigned short*)p)[i]) : ((const float*)p)[i];
}
__device__ __forceinline__ bool det_bf(const unsigned int* mask) {
  return mask[0] != 0x3F800000u;  // fp32 1.0f word; bf16-packed differs
}
__device__ __forceinline__ void gl_lds16(const unsigned short* g, void* l) {
  __builtin_amdgcn_global_load_lds(
      (const __attribute__((address_space(1))) void*)g,
      (__attribute__((address_space(3))) void*)l, 16, 0, 0);
}

// ---------------------------------------------------------------------------
// K0 prep: [0,1024) E->bf16 copy/convert; [1024,1312) weight transposes
// src [512][N] -> dst [Npad][512] bf16, zero-padded rows.
// ---------------------------------------------------------------------------
__global__ __launch_bounds__(256) void prep_kernel(
    const void* __restrict__ E, const void* __restrict__ Wq,
    const void* __restrict__ Wk, const void* __restrict__ Wv,
    const void* __restrict__ Wo, const void* __restrict__ Wl,
    const unsigned int* __restrict__ mask,
    unsigned short* __restrict__ E_c, unsigned short* __restrict__ WqT,
    unsigned short* __restrict__ WkT, unsigned short* __restrict__ WvT,
    unsigned short* __restrict__ WoT, unsigned short* __restrict__ WlT) {
  const bool isbf = det_bf(mask);
  const int tid = threadIdx.x;
  int bi = blockIdx.x;
  if (bi < 1024) {
    const int i0 = (bi * 256 + tid) * 4;
    if (isbf) {
      *(uint2*)&E_c[i0] = *(const uint2*)((const unsigned short*)E + i0);
    } else {
      float4 f = *(const float4*)((const float*)E + i0);
      unsigned short p[4] = {f2bf(f.x), f2bf(f.y), f2bf(f.z), f2bf(f.w)};
      *(uint2*)&E_c[i0] = *(uint2*)p;
    }
    return;
  }
  bi -= 1024;
  const void* src; unsigned short* dst; int N, nb;
  if (bi < 16)       { src = Wq; dst = WqT; N = 64;  nb = bi; }
  else if (bi < 32)  { src = Wk; dst = WkT; N = 64;  nb = bi - 16; }
  else if (bi < 48)  { src = Wv; dst = WvT; N = 64;  nb = bi - 32; }
  else if (bi < 176) { src = Wo; dst = WoT; N = 512; nb = bi - 48; }
  else               { src = Wl; dst = WlT; N = 388; nb = bi - 176; }
  const int n = nb * 4 + (tid >> 6);
  const int k0 = (tid & 63) * 8;
  unsigned short vv[8];
#pragma unroll
  for (int j = 0; j < 8; ++j) {
    if (n >= N) vv[j] = 0;
    else if (isbf) vv[j] = ((const unsigned short*)src)[(size_t)(k0 + j) * N + n];
    else vv[j] = f2bf(((const float*)src)[(size_t)(k0 + j) * N + n]);
  }
  *(uint4*)&dst[(size_t)n * DM_ + k0] = *(uint4*)vv;
}

// ---------------------------------------------------------------------------
// K1: projections. grid (64, 3), tile 64x64, block 256 (4 waves).
// sel 0/1 -> qh/kh row-major bf16 [4096][64]; sel 2 -> vt [B][64][2048] bf16.
// ---------------------------------------------------------------------------
__global__ __launch_bounds__(256) void gemm_proj(
    const void* __restrict__ xq, const void* __restrict__ xk,
    const void* __restrict__ xv,
    const unsigned short* __restrict__ WqT, const unsigned short* __restrict__ WkT,
    const unsigned short* __restrict__ WvT,
    const void* __restrict__ bq, const void* __restrict__ bk,
    const void* __restrict__ bv, const unsigned int* __restrict__ mask,
    unsigned short* __restrict__ oq, unsigned short* __restrict__ ok,
    unsigned short* __restrict__ ovt) {
  __shared__ __align__(16) short sA[64][72];
  __shared__ __align__(16) short sW[64][72];
  const int sel = blockIdx.y;
  const void* x = (sel == 0) ? xq : (sel == 1) ? xk : xv;
  const unsigned short* WT = (sel == 0) ? WqT : (sel == 1) ? WkT : WvT;
  const void* bias = (sel == 0) ? bq : (sel == 1) ? bk : bv;
  const bool isbf = det_bf(mask);

  const int tid = threadIdx.x;
  const int w = tid >> 6, lane = tid & 63;
  const int q_ = lane >> 4, n_ = lane & 15;
  const int row0 = blockIdx.x * 64;

  floatx4 acc[4];
#pragma unroll
  for (int j = 0; j < 4; ++j) acc[j] = (floatx4){0.f, 0.f, 0.f, 0.f};

  for (int k0 = 0; k0 < DM_; k0 += 64) {
    if (isbf) {
#pragma unroll
      for (int it = 0; it < 2; ++it) {
        int idx = tid + it * 256;
        int rr = idx >> 3, cc = (idx & 7) * 8;
        *(uint4*)&sA[rr][cc] =
            *(const uint4*)((const unsigned short*)x + (size_t)(row0 + rr) * DM_ + k0 + cc);
      }
    } else {
#pragma unroll
      for (int it = 0; it < 4; ++it) {
        int idx = tid + it * 256;
        int rr = idx >> 4, cc = (idx & 15) * 4;
        float4 f = *(const float4*)((const float*)x + (size_t)(row0 + rr) * DM_ + k0 + cc);
        unsigned short p[4] = {f2bf(f.x), f2bf(f.y), f2bf(f.z), f2bf(f.w)};
        *(uint2*)&sA[rr][cc] = *(uint2*)p;
      }
    }
#pragma unroll
    for (int it = 0; it < 2; ++it) {
      int idx = tid + it * 256;
      int rr = idx >> 3, cc = (idx & 7) * 8;
      *(uint4*)&sW[rr][cc] = *(const uint4*)(WT + (size_t)rr * DM_ + k0 + cc);
    }
    __syncthreads();
    short8 a0 = *(const short8*)&sA[16 * w + n_][8 * q_];
    short8 a1 = *(const short8*)&sA[16 * w + n_][32 + 8 * q_];
#pragma unroll
    for (int nb = 0; nb < 4; ++nb) {
      short8 b0 = *(const short8*)&sW[16 * nb + n_][8 * q_];
      short8 b1 = *(const short8*)&sW[16 * nb + n_][32 + 8 * q_];
      acc[nb] = MFMA(a0, b0, acc[nb]);
      acc[nb] = MFMA(a1, b1, acc[nb]);
    }
    __syncthreads();
  }

#pragma unroll
  for (int nb = 0; nb < 4; ++nb) {
    const int col = 16 * nb + n_;
    const float bb = ldf(bias, col, isbf);
#pragma unroll
    for (int r = 0; r < 4; ++r) {
      int row = row0 + 16 * w + 4 * q_ + r;
      unsigned short val = f2bf(acc[nb][r] + bb);
      if (sel < 2) {
        unsigned short* o = (sel == 0) ? oq : ok;
        o[(size_t)row * HD_ + col] = val;
      } else {
        int b = row >> 11, s = row & 2047;
        ovt[(((size_t)(b * HD_ + col)) << 11) + s] = val;
      }
    }
  }
}

// ---------------------------------------------------------------------------
// Chunk mapping (R7 table): 80 chunks/hb, grid 1280; hb = id&15,
// rem = 79 - id/16 (LONG chunks get the lowest blockIdx -> dispatched first).
// ti 0..7 -> 1 chunk; 8..15 -> 2; 16..23 -> 3; 24..31 -> 4. Max 8 K-steps.
// Multi-chunk tiles (ti>=8) store partials at slot hb*72 + pbase(ti) + c.
// ---------------------------------------------------------------------------
__device__ __forceinline__ int pbase_of(int ti) {
  return (ti < 16) ? (ti - 8) * 2 : (ti < 24) ? 16 + (ti - 16) * 3
                                              : 40 + (ti - 24) * 4;
}

// ---------------------------------------------------------------------------
// K2: fused causal attention. grid 1280. 4 waves/block, each a 16-row
// q-strip. K/E double-buffered, V triple-buffered (ring) in swizzled LDS,
// all filled by global_load_lds with pre-swizzled global source; one raw
// s_barrier + vmcnt(0) per step. PV of step kt DEFERRED to step kt+1
// (pa-frags in regs across the barrier) so it overlaps the next QK/QE
// instead of serializing after exp->sP. l via all-ones MFMA.
// ---------------------------------------------------------------------------
__global__ __launch_bounds__(256, 2) void attn_kernel(
    const unsigned short* __restrict__ qh, const unsigned short* __restrict__ kh,
    const unsigned short* __restrict__ vt, const unsigned short* __restrict__ E,
    unsigned short* __restrict__ ctxo, float* __restrict__ pc,
    float* __restrict__ ml) {
  __shared__ __align__(16) short sK[2][64][64];    // 16 KB
  __shared__ __align__(16) short sVT[3][64][64];   // 24 KB (ring)
  __shared__ __align__(16) short sE[2][128][64];   // 32 KB
  __shared__ __align__(16) short sP[64][64];       // 8 KB; wave w rows [16w,16w+16)

  const int id = blockIdx.x;
  const int hb = id & 15;        // all chunks of hb share id%8 -> same XCD
  const int rem = 79 - (id >> 4);  // long chunks first in dispatch order
  int ti, c, nc;
  if (rem < 8)       { ti = rem;                 c = 0;            nc = 1; }
  else if (rem < 24) { ti = 8 + ((rem - 8) >> 1);  c = (rem - 8) & 1;  nc = 2; }
  else if (rem < 48) { ti = 16 + (rem - 24) / 3;   c = (rem - 24) % 3; nc = 3; }
  else               { ti = 24 + ((rem - 48) >> 2); c = (rem - 48) & 3; nc = 4; }
  const int nsteps = ti + 1;
  const int klo = (c * nsteps) / nc;
  const int khi = ((c + 1) * nsteps) / nc;

  const int h = hb >> 1, b = hb & 1;
  const int t0 = ti * 64;

  const int tid = threadIdx.x;
  const int w = tid >> 6, lane = tid & 63;
  const int q_ = lane >> 4, n_ = lane & 15;

  const int trow = t0 + 16 * w + n_;
  const unsigned short* qp = qh + (((size_t)((b << 11) + trow)) << 6) + (q_ << 3);
  const short8 qa0 = *(const short8*)qp;
  const short8 qa1 = *(const short8*)(qp + 32);

  short8 onesf;
#pragma unroll
  for (int j = 0; j < 8; ++j) onesf[j] = (short)0x3F80;  // bf16 1.0

  floatx4 ctxa[4];
#pragma unroll
  for (int nb = 0; nb < 4; ++nb) ctxa[nb] = (floatx4){0.f, 0.f, 0.f, 0.f};
  floatx4 lacc = (floatx4){0.f, 0.f, 0.f, 0.f};

  const unsigned short* eb = E + ((size_t)h << 17);
  const unsigned short* kbase = kh + (((size_t)(b << 11)) << 6);
  const unsigned short* vbase = vt + (((size_t)(b << 6)) << 11);

  // DMA staging geometry. Each gl_lds16 covers 8 rows x 8 chunks (64 lanes x
  // 16B, LDS dest linear = base + lane*16B). Source col-chunk pre-XOR'd with
  // row&7 so the linear LDS dest ends up XOR-swizzled.
  const int lrow8 = lane >> 3;                     // 0..7
  const int lch = ((lane & 7) ^ lrow8) << 3;       // swizzled source col
  const int rK0 = 8 * w + lrow8;
  // Swizzled read cols (logical chunk q_ / q_+4 of a row with row%8 == n_&7):
  const int c0s = ((q_ ^ (n_ & 7)) << 3);
  const int c1s = (((q_ | 4) ^ (n_ & 7)) << 3);

#define STAGE(kbuf, vbuf, s0v)                                                 \
  {                                                                            \
    const unsigned short* gK =                                                 \
        kbase + (((size_t)((s0v) + rK0)) << 6) + lch;                          \
    const unsigned short* gV =                                                 \
        vbase + (((size_t)rK0) << 11) + (s0v) + lch;                           \
    gl_lds16(gK, (void*)&sK[kbuf][8 * w][0]);                                  \
    gl_lds16(gK + (32 << 6), (void*)(&sK[kbuf][8 * w][0] + 32 * 64));          \
    gl_lds16(gV, (void*)&sVT[vbuf][8 * w][0]);                                 \
    gl_lds16(gV + (32 << 11), (void*)(&sVT[vbuf][8 * w][0] + 32 * 64));        \
    const int rbE = (T_ - 64) + (s0v)-t0;                                      \
    _Pragma("unroll") for (int off = 0; off < 4; ++off) {                      \
      int gr = rbE + 32 * w + 8 * off + lrow8;                                 \
      if (gr > T_ - 1) gr = T_ - 1; /* clamped rows are masked s>t */          \
      gl_lds16(eb + ((size_t)gr << 6) + lch,                                   \
               (void*)&sE[kbuf][32 * w + 8 * off][0]);                         \
    }                                                                          \
  }

  // Prologue: stage first K/V/E tile (naked latency, once per block).
  STAGE(0, 0, klo * 64);

  short8 pa0p = {0, 0, 0, 0, 0, 0, 0, 0};  // deferred-PV fragments,
  short8 pa1p = {0, 0, 0, 0, 0, 0, 0, 0};  // carried across the barrier

  for (int kt = klo; kt < khi; ++kt) {
    const int ph = (kt - klo) & 1;       // K/E double-buffer phase
    const int vcur = (kt - klo) % 3;     // V ring slot of this step
    const int s0 = kt * 64;

    // Own DMA for this step complete -> publish to all waves.
    asm volatile("s_waitcnt vmcnt(0)" ::: "memory");
    __builtin_amdgcn_sched_barrier(0);
    __builtin_amdgcn_s_barrier();
    __builtin_amdgcn_sched_barrier(0);

    // Issue next tile's DMA (lands during this step's compute).
    if (kt + 1 < khi) STAGE(ph ^ 1, (kt + 1 - klo) % 3, s0 + 64);

    // ---- QK MFMA from LDS K ----
    floatx4 qk[4];
    __builtin_amdgcn_s_setprio(1);
#pragma unroll
    for (int nb = 0; nb < 4; ++nb) {
      short8 kb0 = *(const short8*)&sK[ph][16 * nb + n_][c0s];
      short8 kb1 = *(const short8*)&sK[ph][16 * nb + n_][c1s];
      qk[nb] = (floatx4){0.f, 0.f, 0.f, 0.f};
      qk[nb] = MFMA(qa0, kb0, qk[nb]);
      qk[nb] = MFMA(qa1, kb1, qk[nb]);
    }
    // ---- QE MFMA from LDS E window ----
    floatx4 qe[5];
#pragma unroll
    for (int f = 0; f < 5; ++f) {
      const short* ep = &sE[ph][16 * (3 - w + f) + n_][0];
      short8 eb0 = *(const short8*)(ep + c0s);
      short8 eb1 = *(const short8*)(ep + c1s);
      qe[f] = (floatx4){0.f, 0.f, 0.f, 0.f};
      qe[f] = MFMA(qa0, eb0, qe[f]);
      qe[f] = MFMA(qa1, eb1, qe[f]);
    }
    // ---- deferred PV + l for step kt-1 (independent of this step's QK/QE;
    //      fills their latency shadow). Reads V ring slot (vcur+2)%3. ----
    if (kt > klo) {
      const int vprev = (vcur + 2) % 3;
#pragma unroll
      for (int nb = 0; nb < 4; ++nb) {
        short8 v0 = *(const short8*)&sVT[vprev][16 * nb + n_][c0s];
        short8 v1 = *(const short8*)&sVT[vprev][16 * nb + n_][c1s];
        ctxa[nb] = MFMA(pa0p, v0, ctxa[nb]);
        ctxa[nb] = MFMA(pa1p, v1, ctxa[nb]);
      }
      lacc = MFMA(pa0p, onesf, lacc);
      lacc = MFMA(pa1p, onesf, lacc);
    }
    __builtin_amdgcn_s_setprio(0);

    // ---- skew diagonal (16 bpermute, source-side frag select) + exp + sP --
    const bool diag = (kt == ti);
#pragma unroll
    for (int r = 0; r < 4; ++r) {
      const int t = 4 * q_ + r;
      const int ba = ((q_ << 4) | ((n_ - t + 15) & 15)) << 2;
      const int nd = (n_ + t + 1) & 15;   // dest lane (same q_) pulling from us
      const bool hi = nd > t;             // dest picks qe[mb+1] iff its n_ > t
      const int swr = (t & 7) << 3;       // sP row-swizzle term
#pragma unroll
      for (int mb = 0; mb < 4; ++mb) {
        float merged = hi ? qe[mb + 1][r] : qe[mb][r];
        float g = __int_as_float(
            __builtin_amdgcn_ds_bpermute(ba, __float_as_int(merged)));
        float sv = qk[mb][r] + g;
        if (diag && (16 * mb + n_ > 16 * w + t)) sv = -1.0e30f;  // exp -> 0
        // exp(sv*0.125) == exp2(sv * 0.125*log2(e))
        sP[16 * w + t][(16 * mb + n_) ^ swr] =
            (short)f2bf(exp2f(sv * 0.18033688011f));
      }
    }

    // ---- read own P strip into regs for NEXT step's deferred PV ----
    pa0p = *(const short8*)&sP[16 * w + n_][c0s];
    pa1p = *(const short8*)&sP[16 * w + n_][c1s];
  }
#undef STAGE

  // ---- epilogue: PV + l for the last step ----
  {
    const int vlast = (khi - 1 - klo) % 3;
    __builtin_amdgcn_s_setprio(1);
#pragma unroll
    for (int nb = 0; nb < 4; ++nb) {
      short8 v0 = *(const short8*)&sVT[vlast][16 * nb + n_][c0s];
      short8 v1 = *(const short8*)&sVT[vlast][16 * nb + n_][c1s];
      ctxa[nb] = MFMA(pa0p, v0, ctxa[nb]);
      ctxa[nb] = MFMA(pa1p, v1, ctxa[nb]);
    }
    lacc = MFMA(pa0p, onesf, lacc);
    lacc = MFMA(pa1p, onesf, lacc);
    __builtin_amdgcn_s_setprio(0);
  }

  if (nc == 1) {
#pragma unroll
    for (int r = 0; r < 4; ++r) {
      const float inv = 1.0f / lacc[r];
      const int row = t0 + 16 * w + 4 * q_ + r;
      const size_t base = (((size_t)((b << 11) + row)) << 9) + (h << 6) + n_;
#pragma unroll
      for (int nb = 0; nb < 4; ++nb)
        ctxo[base + 16 * nb] = f2bf(ctxa[nb][r] * inv);
    }
  } else {
    const int idx = hb * 72 + pbase_of(ti) + c;
    float* pcb = pc + ((size_t)idx << 12);   // *4096
    float* mlb = ml + ((size_t)idx << 6);    // *64
#pragma unroll
    for (int r = 0; r < 4; ++r) {
      const int row = 16 * w + 4 * q_ + r;
#pragma unroll
      for (int nb = 0; nb < 4; ++nb)
        pcb[(row << 6) + 16 * nb + n_] = ctxa[nb][r];
      if (n_ == 0) mlb[row] = lacc[r];
    }
  }
}

// ---------------------------------------------------------------------------
// K2b: combine chunk partials: out = sum(c_i) / sum(l_i). grid 384 blocks
// (16 hb x 24 multi-chunk tiles, ti 8..31).
// ---------------------------------------------------------------------------
__global__ __launch_bounds__(256) void combine_kernel(
    const float* __restrict__ pc, const float* __restrict__ ml,
    unsigned short* __restrict__ ctxo) {
  const int cb = blockIdx.x;
  const int hb = cb / 24;
  const int ti = 8 + cb % 24;
  const int nc = (ti >> 3) + 1;
  const int h = hb >> 1, b = hb & 1, t0 = ti * 64;
  const int tid = threadIdx.x;
  const int row = tid >> 2, seg = (tid & 3) * 16;
  const int idx0 = hb * 72 + pbase_of(ti);

  float lsum = 0.f;
  float4 a4[4];
#pragma unroll
  for (int j = 0; j < 4; ++j) a4[j] = (float4){0.f, 0.f, 0.f, 0.f};
  for (int c = 0; c < nc; ++c) {
    const int idx = idx0 + c;
    lsum += ml[((size_t)idx << 6) + row];
    const float* cp = pc + ((size_t)idx << 12) + (row << 6) + seg;
#pragma unroll
    for (int j = 0; j < 4; ++j) {
      float4 x = *(const float4*)(cp + 4 * j);
      a4[j].x += x.x; a4[j].y += x.y; a4[j].z += x.z; a4[j].w += x.w;
    }
  }
  const float inv = 1.0f / lsum;
  unsigned short o[16];
#pragma unroll
  for (int j = 0; j < 4; ++j) {
    o[4 * j + 0] = f2bf(a4[j].x * inv);
    o[4 * j + 1] = f2bf(a4[j].y * inv);
    o[4 * j + 2] = f2bf(a4[j].z * inv);
    o[4 * j + 3] = f2bf(a4[j].w * inv);
  }
  unsigned short* dst =
      ctxo + (((size_t)((b << 11) + t0 + row)) << 9) + (h << 6) + seg;
  *(uint4*)dst = *(uint4*)&o[0];
  *(uint4*)(dst + 8) = *(uint4*)&o[8];
}

// ---------------------------------------------------------------------------
// K3: MFMA GEMM, A bf16 [4096][512] @ WT bf16 [Npad][512] + bias, tile 64x64.
// RELU=1: out h1 bf16 [4096][512]. RELU=0: out d_out (dtype per mask), N=388.
// ---------------------------------------------------------------------------
template <int RELU>
__global__ __launch_bounds__(256) void mlp_mfma(
    const unsigned short* __restrict__ A, const unsigned short* __restrict__ WT,
    const void* __restrict__ bias, unsigned short* __restrict__ outBF,
    void* __restrict__ outD, const unsigned int* __restrict__ mask) {
  __shared__ __align__(16) short sA[64][72];
  __shared__ __align__(16) short sW[64][72];
  const int tid = threadIdx.x;
  const int w = tid >> 6, lane = tid & 63;
  const int q_ = lane >> 4, n_ = lane & 15;
  const int row0 = blockIdx.x * 64;
  const int n0 = blockIdx.y * 64;
  const bool isbf = det_bf(mask);

  floatx4 acc[4];
#pragma unroll
  for (int j = 0; j < 4; ++j) acc[j] = (floatx4){0.f, 0.f, 0.f, 0.f};

  for (int k0 = 0; k0 < DM_; k0 += 64) {
#pragma unroll
    for (int it = 0; it < 2; ++it) {
      int idx = tid + it * 256;
      int rr = idx >> 3, cc = (idx & 7) * 8;
      *(uint4*)&sA[rr][cc] = *(const uint4*)(A + (size_t)(row0 + rr) * DM_ + k0 + cc);
      *(uint4*)&sW[rr][cc] = *(const uint4*)(WT + (size_t)(n0 + rr) * DM_ + k0 + cc);
    }
    __syncthreads();
    short8 a0 = *(const short8*)&sA[16 * w + n_][8 * q_];
    short8 a1 = *(const short8*)&sA[16 * w + n_][32 + 8 * q_];
#pragma unroll
    for (int nb = 0; nb < 4; ++nb) {
      short8 b0 = *(const short8*)&sW[16 * nb + n_][8 * q_];
      short8 b1 = *(const short8*)&sW[16 * nb + n_][32 + 8 * q_];
      acc[nb] = MFMA(a0, b0, acc[nb]);
      acc[nb] = MFMA(a1, b1, acc[nb]);
    }
    __syncthreads();
  }

#pragma unroll
  for (int nb = 0; nb < 4; ++nb) {
    const int col = n0 + 16 * nb + n_;
    float bb = 0.f;
    if (RELU || col < EV_) bb = ldf(bias, col, isbf);
#pragma unroll
    for (int r = 0; r < 4; ++r) {
      const int row = row0 + 16 * w + 4 * q_ + r;
      float v = acc[nb][r] + bb;
      if (RELU) {
        outBF[(size_t)row * ED_ + col] = f2bf(fmaxf(v, 0.f));
      } else if (col < EV_) {
        if (isbf) ((unsigned short*)outD)[(size_t)row * EV_ + col] = f2bf(v);
        else      ((float*)outD)[(size_t)row * EV_ + col] = v;
      }
    }
  }
}

// ---------------------------------------------------------------------------
extern "C" void kernel_launch(void* const* d_in, const int* in_sizes, int n_in,
                              void* d_out, int out_size, void* d_ws, size_t ws_size,
                              hipStream_t stream) {
  const void* v  = d_in[0];
  const void* k  = d_in[1];
  const void* q  = d_in[2];
  const unsigned int* mask = (const unsigned int*)d_in[3];
  const void* Wq = d_in[4];
  const void* bq = d_in[5];
  const void* Wk = d_in[6];
  const void* bk = d_in[7];
  const void* Wv = d_in[8];
  const void* bv = d_in[9];
  const void* E  = d_in[10];
  const void* Wo = d_in[11];
  const void* bo = d_in[12];
  const void* Wl = d_in[13];
  const void* bl = d_in[14];

  char* p = (char*)d_ws;
  unsigned short* E_c  = (unsigned short*)p; p += (size_t)H_ * T_ * HD_ * 2;  // 2 MB
  unsigned short* qhb  = (unsigned short*)p; p += (size_t)BT_ * HD_ * 2;
  unsigned short* khb  = (unsigned short*)p; p += (size_t)BT_ * HD_ * 2;
  unsigned short* vtb  = (unsigned short*)p; p += (size_t)BT_ * HD_ * 2;
  unsigned short* WqT  = (unsigned short*)p; p += (size_t)HD_ * DM_ * 2;
  unsigned short* WkT  = (unsigned short*)p; p += (size_t)HD_ * DM_ * 2;
  unsigned short* WvT  = (unsigned short*)p; p += (size_t)HD_ * DM_ * 2;
  unsigned short* WoT  = (unsigned short*)p; p += (size_t)ED_ * DM_ * 2;
  unsigned short* WlT  = (unsigned short*)p; p += (size_t)448 * DM_ * 2;
  unsigned short* ctxb = (unsigned short*)p; p += (size_t)BT_ * DM_ * 2;      // 4 MB
  unsigned short* h1b  = (unsigned short*)p; p += (size_t)BT_ * ED_ * 2;      // 4 MB
  float* pc = (float*)p; p += (size_t)16 * 72 * 4096 * 4;                     // 18.9 MB
  float* ml = (float*)p; p += (size_t)16 * 72 * 64 * 4;                       // 0.3 MB

  prep_kernel<<<dim3(1312), 256, 0, stream>>>(
      E, Wq, Wk, Wv, Wo, Wl, mask, E_c, WqT, WkT, WvT, WoT, WlT);
  gemm_proj<<<dim3(BT_ / 64, 3), 256, 0, stream>>>(
      q, k, v, WqT, WkT, WvT, bq, bk, bv, mask, qhb, khb, vtb);
  attn_kernel<<<dim3(1280), 256, 0, stream>>>(qhb, khb, vtb, E_c, ctxb, pc, ml);
  combine_kernel<<<dim3(384), 256, 0, stream>>>(pc, ml, ctxb);
  mlp_mfma<1><<<dim3(BT_ / 64, ED_ / 64), 256, 0, stream>>>(
      ctxb, WoT, bo, h1b, nullptr, mask);
  mlp_mfma<0><<<dim3(BT_ / 64, 448 / 64), 256, 0, stream>>>(
      h1b, WlT, bl, nullptr, d_out, mask);
}

// Round 9
// 203.759 us; speedup vs baseline: 1.1579x; 1.0143x over previous
//
#include <hip/hip_runtime.h>
#include <hip/hip_bf16.h>

// Music-Transformer RelativeGlobalAttention, MI355X round 16.
// B=2, T=2048, D=512, H=8, hd=64, ED=512, EV=388. fp32 I/O (runtime-detected
// via mask[0] bit pattern), bf16 MFMA compute, fp32 accumulation.
// R16 = R15 (55us attn: DMA-staged K/V/E, deferred PV) + T4 counted vmcnt
// (m233: in 2-phase schedules stage+vmcnt(0)+barrier is ~72% of step time;
// never drain to 0 in the main loop) + E panel ring (stage 1 new 64-row
// panel/step instead of 128 rows; E DMA halves).
//  - STAGE issue order pinned K(2)->E(2)->V(2) via sched_barrier so vmcnt
//    FIFO arithmetic holds: top vmcnt(4) = {K(s) done, V(s-1) done} -> phase
//    A: QK + deferred PV; mid vmcnt(8|2) = {E(s) done} -> phase B: QE + skew
//    + sP. V(s) stays in flight across the whole step; vmcnt(0) only in the
//    epilogue. 2 barriers/step.
//  - sE[3][64][64] ring (window = panels [P,P+1], P=31+kt-ti, 64-aligned;
//    stage panel P+2 during step kt). LDS 80->72KB, still 2 blocks/CU.

#define B_ 2
#define T_ 2048
#define DM_ 512
#define H_ 8
#define HD_ 64
#define ED_ 512
#define EV_ 388
#define BT_ (B_ * T_)

typedef __attribute__((ext_vector_type(8))) short short8;
typedef __attribute__((ext_vector_type(4))) float floatx4;

#define MFMA(a, b, c) __builtin_amdgcn_mfma_f32_16x16x32_bf16((a), (b), (c), 0, 0, 0)

__device__ __forceinline__ float bfs(unsigned short s) {
  union { unsigned int i; float f; } v; v.i = ((unsigned int)s) << 16; return v.f;
}
__device__ __forceinline__ unsigned short f2bf(float f) {
  __hip_bfloat16 h = __float2bfloat16(f);
  union { __hip_bfloat16 h; unsigned short u; } v; v.h = h; return v.u;
}
__device__ __forceinline__ float ldf(const void* p, int i, bool isbf) {
  return isbf ? bfs(((const unsigned short*)p)[i]) : ((const float*)p)[i];
}
__device__ __forceinline__ bool det_bf(const unsigned int* mask) {
  return mask[0] != 0x3F800000u;  // fp32 1.0f word; bf16-packed differs
}
__device__ __forceinline__ void gl_lds16(const unsigned short* g, void* l) {
  __builtin_amdgcn_global_load_lds(
      (const __attribute__((address_space(1))) void*)g,
      (__attribute__((address_space(3))) void*)l, 16, 0, 0);
}

// ---------------------------------------------------------------------------
// K0 prep: [0,1024) E->bf16 copy/convert; [1024,1312) weight transposes
// src [512][N] -> dst [Npad][512] bf16, zero-padded rows.
// ---------------------------------------------------------------------------
__global__ __launch_bounds__(256) void prep_kernel(
    const void* __restrict__ E, const void* __restrict__ Wq,
    const void* __restrict__ Wk, const void* __restrict__ Wv,
    const void* __restrict__ Wo, const void* __restrict__ Wl,
    const unsigned int* __restrict__ mask,
    unsigned short* __restrict__ E_c, unsigned short* __restrict__ WqT,
    unsigned short* __restrict__ WkT, unsigned short* __restrict__ WvT,
    unsigned short* __restrict__ WoT, unsigned short* __restrict__ WlT) {
  const bool isbf = det_bf(mask);
  const int tid = threadIdx.x;
  int bi = blockIdx.x;
  if (bi < 1024) {
    const int i0 = (bi * 256 + tid) * 4;
    if (isbf) {
      *(uint2*)&E_c[i0] = *(const uint2*)((const unsigned short*)E + i0);
    } else {
      float4 f = *(const float4*)((const float*)E + i0);
      unsigned short p[4] = {f2bf(f.x), f2bf(f.y), f2bf(f.z), f2bf(f.w)};
      *(uint2*)&E_c[i0] = *(uint2*)p;
    }
    return;
  }
  bi -= 1024;
  const void* src; unsigned short* dst; int N, nb;
  if (bi < 16)       { src = Wq; dst = WqT; N = 64;  nb = bi; }
  else if (bi < 32)  { src = Wk; dst = WkT; N = 64;  nb = bi - 16; }
  else if (bi < 48)  { src = Wv; dst = WvT; N = 64;  nb = bi - 32; }
  else if (bi < 176) { src = Wo; dst = WoT; N = 512; nb = bi - 48; }
  else               { src = Wl; dst = WlT; N = 388; nb = bi - 176; }
  const int n = nb * 4 + (tid >> 6);
  const int k0 = (tid & 63) * 8;
  unsigned short vv[8];
#pragma unroll
  for (int j = 0; j < 8; ++j) {
    if (n >= N) vv[j] = 0;
    else if (isbf) vv[j] = ((const unsigned short*)src)[(size_t)(k0 + j) * N + n];
    else vv[j] = f2bf(((const float*)src)[(size_t)(k0 + j) * N + n]);
  }
  *(uint4*)&dst[(size_t)n * DM_ + k0] = *(uint4*)vv;
}

// ---------------------------------------------------------------------------
// K1: projections. grid (64, 3), tile 64x64, block 256 (4 waves).
// sel 0/1 -> qh/kh row-major bf16 [4096][64]; sel 2 -> vt [B][64][2048] bf16.
// ---------------------------------------------------------------------------
__global__ __launch_bounds__(256) void gemm_proj(
    const void* __restrict__ xq, const void* __restrict__ xk,
    const void* __restrict__ xv,
    const unsigned short* __restrict__ WqT, const unsigned short* __restrict__ WkT,
    const unsigned short* __restrict__ WvT,
    const void* __restrict__ bq, const void* __restrict__ bk,
    const void* __restrict__ bv, const unsigned int* __restrict__ mask,
    unsigned short* __restrict__ oq, unsigned short* __restrict__ ok,
    unsigned short* __restrict__ ovt) {
  __shared__ __align__(16) short sA[64][72];
  __shared__ __align__(16) short sW[64][72];
  const int sel = blockIdx.y;
  const void* x = (sel == 0) ? xq : (sel == 1) ? xk : xv;
  const unsigned short* WT = (sel == 0) ? WqT : (sel == 1) ? WkT : WvT;
  const void* bias = (sel == 0) ? bq : (sel == 1) ? bk : bv;
  const bool isbf = det_bf(mask);

  const int tid = threadIdx.x;
  const int w = tid >> 6, lane = tid & 63;
  const int q_ = lane >> 4, n_ = lane & 15;
  const int row0 = blockIdx.x * 64;

  floatx4 acc[4];
#pragma unroll
  for (int j = 0; j < 4; ++j) acc[j] = (floatx4){0.f, 0.f, 0.f, 0.f};

  for (int k0 = 0; k0 < DM_; k0 += 64) {
    if (isbf) {
#pragma unroll
      for (int it = 0; it < 2; ++it) {
        int idx = tid + it * 256;
        int rr = idx >> 3, cc = (idx & 7) * 8;
        *(uint4*)&sA[rr][cc] =
            *(const uint4*)((const unsigned short*)x + (size_t)(row0 + rr) * DM_ + k0 + cc);
      }
    } else {
#pragma unroll
      for (int it = 0; it < 4; ++it) {
        int idx = tid + it * 256;
        int rr = idx >> 4, cc = (idx & 15) * 4;
        float4 f = *(const float4*)((const float*)x + (size_t)(row0 + rr) * DM_ + k0 + cc);
        unsigned short p[4] = {f2bf(f.x), f2bf(f.y), f2bf(f.z), f2bf(f.w)};
        *(uint2*)&sA[rr][cc] = *(uint2*)p;
      }
    }
#pragma unroll
    for (int it = 0; it < 2; ++it) {
      int idx = tid + it * 256;
      int rr = idx >> 3, cc = (idx & 7) * 8;
      *(uint4*)&sW[rr][cc] = *(const uint4*)(WT + (size_t)rr * DM_ + k0 + cc);
    }
    __syncthreads();
    short8 a0 = *(const short8*)&sA[16 * w + n_][8 * q_];
    short8 a1 = *(const short8*)&sA[16 * w + n_][32 + 8 * q_];
#pragma unroll
    for (int nb = 0; nb < 4; ++nb) {
      short8 b0 = *(const short8*)&sW[16 * nb + n_][8 * q_];
      short8 b1 = *(const short8*)&sW[16 * nb + n_][32 + 8 * q_];
      acc[nb] = MFMA(a0, b0, acc[nb]);
      acc[nb] = MFMA(a1, b1, acc[nb]);
    }
    __syncthreads();
  }

#pragma unroll
  for (int nb = 0; nb < 4; ++nb) {
    const int col = 16 * nb + n_;
    const float bb = ldf(bias, col, isbf);
#pragma unroll
    for (int r = 0; r < 4; ++r) {
      int row = row0 + 16 * w + 4 * q_ + r;
      unsigned short val = f2bf(acc[nb][r] + bb);
      if (sel < 2) {
        unsigned short* o = (sel == 0) ? oq : ok;
        o[(size_t)row * HD_ + col] = val;
      } else {
        int b = row >> 11, s = row & 2047;
        ovt[(((size_t)(b * HD_ + col)) << 11) + s] = val;
      }
    }
  }
}

// ---------------------------------------------------------------------------
// Chunk mapping (R7 table): 80 chunks/hb, grid 1280; hb = id&15,
// rem = 79 - id/16 (LONG chunks get the lowest blockIdx -> dispatched first).
// ti 0..7 -> 1 chunk; 8..15 -> 2; 16..23 -> 3; 24..31 -> 4. Max 8 K-steps.
// Multi-chunk tiles (ti>=8) store partials at slot hb*72 + pbase(ti) + c.
// ---------------------------------------------------------------------------
__device__ __forceinline__ int pbase_of(int ti) {
  return (ti < 16) ? (ti - 8) * 2 : (ti < 24) ? 16 + (ti - 16) * 3
                                              : 40 + (ti - 24) * 4;
}

// ---------------------------------------------------------------------------
// K2: fused causal attention. grid 1280, 4 waves/block, 16-row q-strips.
// K double-buffered, V + E-panel triple-buffered rings, all DMA-staged with
// pre-swizzled source. Counted-vmcnt phase split (see header). Deferred PV.
// ---------------------------------------------------------------------------
__global__ __launch_bounds__(256, 2) void attn_kernel(
    const unsigned short* __restrict__ qh, const unsigned short* __restrict__ kh,
    const unsigned short* __restrict__ vt, const unsigned short* __restrict__ E,
    unsigned short* __restrict__ ctxo, float* __restrict__ pc,
    float* __restrict__ ml) {
  __shared__ __align__(16) short sK[2][64][64];    // 16 KB
  __shared__ __align__(16) short sVT[3][64][64];   // 24 KB (ring)
  __shared__ __align__(16) short sE3[3][64][64];   // 24 KB (panel ring)
  __shared__ __align__(16) short sP[64][64];       // 8 KB; wave w rows [16w,16w+16)

  const int id = blockIdx.x;
  const int hb = id & 15;        // all chunks of hb share id%8 -> same XCD
  const int rem = 79 - (id >> 4);  // long chunks first in dispatch order
  int ti, c, nc;
  if (rem < 8)       { ti = rem;                 c = 0;            nc = 1; }
  else if (rem < 24) { ti = 8 + ((rem - 8) >> 1);  c = (rem - 8) & 1;  nc = 2; }
  else if (rem < 48) { ti = 16 + (rem - 24) / 3;   c = (rem - 24) % 3; nc = 3; }
  else               { ti = 24 + ((rem - 48) >> 2); c = (rem - 48) & 3; nc = 4; }
  const int nsteps = ti + 1;
  const int klo = (c * nsteps) / nc;
  const int khi = ((c + 1) * nsteps) / nc;

  const int h = hb >> 1, b = hb & 1;
  const int t0 = ti * 64;

  const int tid = threadIdx.x;
  const int w = tid >> 6, lane = tid & 63;
  const int q_ = lane >> 4, n_ = lane & 15;

  const int trow = t0 + 16 * w + n_;
  const unsigned short* qp = qh + (((size_t)((b << 11) + trow)) << 6) + (q_ << 3);
  const short8 qa0 = *(const short8*)qp;
  const short8 qa1 = *(const short8*)(qp + 32);

  short8 onesf;
#pragma unroll
  for (int j = 0; j < 8; ++j) onesf[j] = (short)0x3F80;  // bf16 1.0

  floatx4 ctxa[4];
#pragma unroll
  for (int nb = 0; nb < 4; ++nb) ctxa[nb] = (floatx4){0.f, 0.f, 0.f, 0.f};
  floatx4 lacc = (floatx4){0.f, 0.f, 0.f, 0.f};

  const unsigned short* eb = E + ((size_t)h << 17);
  const unsigned short* kbase = kh + (((size_t)(b << 11)) << 6);
  const unsigned short* vbase = vt + (((size_t)(b << 6)) << 11);

  // DMA staging geometry. Each gl_lds16 covers 8 rows x 8 chunks (64 lanes x
  // 16B, LDS dest linear). Source col-chunk pre-XOR'd with row&7 so the
  // linear LDS dest ends up XOR-swizzled.
  const int lrow8 = lane >> 3;                     // 0..7
  const int lch = ((lane & 7) ^ lrow8) << 3;       // swizzled source col
  const int rK0 = 8 * w + lrow8;
  // Swizzled read cols (logical chunk q_ / q_+4 of a row with row%8 == n_&7):
  const int c0s = ((q_ ^ (n_ & 7)) << 3);
  const int c1s = (((q_ | 4) ^ (n_ & 7)) << 3);

// Issue-order-pinned staging groups (vmcnt FIFO arithmetic depends on order):
#define STAGE_K(kbuf, s0v)                                                     \
  {                                                                            \
    const unsigned short* gK =                                                 \
        kbase + (((size_t)((s0v) + rK0)) << 6) + lch;                          \
    gl_lds16(gK, (void*)&sK[kbuf][8 * w][0]);                                  \
    gl_lds16(gK + (32 << 6), (void*)(&sK[kbuf][8 * w][0] + 32 * 64));          \
  }
#define STAGE_E(slot, panel)                                                   \
  {                                                                            \
    _Pragma("unroll") for (int j = 0; j < 2; ++j) {                            \
      int gr = 64 * (panel) + 16 * w + 8 * j + lrow8;                          \
      if (gr > T_ - 1) gr = T_ - 1; /* clamped rows are masked s>t */          \
      gl_lds16(eb + ((size_t)gr << 6) + lch,                                   \
               (void*)&sE3[slot][16 * w + 8 * j][0]);                          \
    }                                                                          \
  }
#define STAGE_V(vbuf, s0v)                                                     \
  {                                                                            \
    const unsigned short* gV =                                                 \
        vbase + (((size_t)rK0) << 11) + (s0v) + lch;                           \
    gl_lds16(gV, (void*)&sVT[vbuf][8 * w][0]);                                 \
    gl_lds16(gV + (32 << 11), (void*)(&sVT[vbuf][8 * w][0] + 32 * 64));        \
  }

  // Prologue (issue order K, E, E, V -> 8 outstanding; no drain needed,
  // the loop's counted waits cover it).
  {
    const int p0 = 31 + klo - ti;       // first window panel (>= 0)
    STAGE_K(0, klo * 64);
    __builtin_amdgcn_sched_barrier(0);
    STAGE_E(p0 % 3, p0);
    STAGE_E((p0 + 1) % 3, p0 + 1);
    __builtin_amdgcn_sched_barrier(0);
    STAGE_V(0, klo * 64);
  }

  short8 pa0p = {0, 0, 0, 0, 0, 0, 0, 0};  // deferred-PV fragments,
  short8 pa1p = {0, 0, 0, 0, 0, 0, 0, 0};  // carried across the barrier

  for (int kt = klo; kt < khi; ++kt) {
    const int ph = (kt - klo) & 1;       // K double-buffer phase
    const int vcur = (kt - klo) % 3;     // V ring slot of this step
    const int s0 = kt * 64;
    const int pk = 31 + kt - ti;         // current window panel index
    const int slotA = pk % 3;            // rows 0..63 of window
    const int slotB = (pk + 1) % 3;      // rows 64..127

    // ---- phase A top: K(s) + V(s-1) retired (4 newest = E(s),V(s)) ----
    asm volatile("s_waitcnt vmcnt(4)" ::: "memory");
    __builtin_amdgcn_sched_barrier(0);
    __builtin_amdgcn_s_barrier();
    __builtin_amdgcn_sched_barrier(0);

    // Issue next step's staging (K -> E -> V, order pinned).
    if (kt + 1 < khi) {
      STAGE_K(ph ^ 1, s0 + 64);
      __builtin_amdgcn_sched_barrier(0);
      STAGE_E((pk + 2) % 3, pk + 2);
      __builtin_amdgcn_sched_barrier(0);
      STAGE_V((kt + 1 - klo) % 3, s0 + 64);
    }

    // ---- QK MFMA from LDS K ----
    floatx4 qk[4];
    __builtin_amdgcn_s_setprio(1);
#pragma unroll
    for (int nb = 0; nb < 4; ++nb) {
      short8 kb0 = *(const short8*)&sK[ph][16 * nb + n_][c0s];
      short8 kb1 = *(const short8*)&sK[ph][16 * nb + n_][c1s];
      qk[nb] = (floatx4){0.f, 0.f, 0.f, 0.f};
      qk[nb] = MFMA(qa0, kb0, qk[nb]);
      qk[nb] = MFMA(qa1, kb1, qk[nb]);
    }
    // ---- deferred PV + l for step kt-1 (V(s-1) retired at phase-A top) ----
    if (kt > klo) {
      const int vprev = (vcur + 2) % 3;
#pragma unroll
      for (int nb = 0; nb < 4; ++nb) {
        short8 v0 = *(const short8*)&sVT[vprev][16 * nb + n_][c0s];
        short8 v1 = *(const short8*)&sVT[vprev][16 * nb + n_][c1s];
        ctxa[nb] = MFMA(pa0p, v0, ctxa[nb]);
        ctxa[nb] = MFMA(pa1p, v1, ctxa[nb]);
      }
      lacc = MFMA(pa0p, onesf, lacc);
      lacc = MFMA(pa1p, onesf, lacc);
    }
    __builtin_amdgcn_s_setprio(0);

    // ---- phase B: E(s) retired (leave V(s) [+ next STAGE] in flight) ----
    if (kt + 1 < khi) {
      asm volatile("s_waitcnt vmcnt(8)" ::: "memory");
    } else {
      asm volatile("s_waitcnt vmcnt(2)" ::: "memory");
    }
    __builtin_amdgcn_sched_barrier(0);
    __builtin_amdgcn_s_barrier();
    __builtin_amdgcn_sched_barrier(0);

    // ---- QE MFMA from E panel ring ----
    floatx4 qe[5];
#pragma unroll
    for (int f = 0; f < 5; ++f) {
      const int row16 = 16 * (3 - w + f);          // 0..112, 16-aligned
      const short* ep = (row16 < 64) ? &sE3[slotA][row16 + n_][0]
                                     : &sE3[slotB][row16 - 64 + n_][0];
      short8 eb0 = *(const short8*)(ep + c0s);
      short8 eb1 = *(const short8*)(ep + c1s);
      qe[f] = (floatx4){0.f, 0.f, 0.f, 0.f};
      __builtin_amdgcn_s_setprio(1);
      qe[f] = MFMA(qa0, eb0, qe[f]);
      qe[f] = MFMA(qa1, eb1, qe[f]);
      __builtin_amdgcn_s_setprio(0);
    }

    // ---- skew diagonal (16 bpermute, source-side frag select) + exp + sP --
    const bool diag = (kt == ti);
#pragma unroll
    for (int r = 0; r < 4; ++r) {
      const int t = 4 * q_ + r;
      const int ba = ((q_ << 4) | ((n_ - t + 15) & 15)) << 2;
      const int nd = (n_ + t + 1) & 15;   // dest lane (same q_) pulling from us
      const bool hi = nd > t;             // dest picks qe[mb+1] iff its n_ > t
      const int swr = (t & 7) << 3;       // sP row-swizzle term
#pragma unroll
      for (int mb = 0; mb < 4; ++mb) {
        float merged = hi ? qe[mb + 1][r] : qe[mb][r];
        float g = __int_as_float(
            __builtin_amdgcn_ds_bpermute(ba, __float_as_int(merged)));
        float sv = qk[mb][r] + g;
        if (diag && (16 * mb + n_ > 16 * w + t)) sv = -1.0e30f;  // exp -> 0
        // exp(sv*0.125) == exp2(sv * 0.125*log2(e))
        sP[16 * w + t][(16 * mb + n_) ^ swr] =
            (short)f2bf(exp2f(sv * 0.18033688011f));
      }
    }

    // ---- read own P strip into regs for NEXT step's deferred PV ----
    pa0p = *(const short8*)&sP[16 * w + n_][c0s];
    pa1p = *(const short8*)&sP[16 * w + n_][c1s];
  }
#undef STAGE_K
#undef STAGE_E
#undef STAGE_V

  // ---- epilogue: V(khi-1) fully retired, then last PV + l ----
  asm volatile("s_waitcnt vmcnt(0)" ::: "memory");
  __builtin_amdgcn_sched_barrier(0);
  __builtin_amdgcn_s_barrier();
  __builtin_amdgcn_sched_barrier(0);
  {
    const int vlast = (khi - 1 - klo) % 3;
    __builtin_amdgcn_s_setprio(1);
#pragma unroll
    for (int nb = 0; nb < 4; ++nb) {
      short8 v0 = *(const short8*)&sVT[vlast][16 * nb + n_][c0s];
      short8 v1 = *(const short8*)&sVT[vlast][16 * nb + n_][c1s];
      ctxa[nb] = MFMA(pa0p, v0, ctxa[nb]);
      ctxa[nb] = MFMA(pa1p, v1, ctxa[nb]);
    }
    lacc = MFMA(pa0p, onesf, lacc);
    lacc = MFMA(pa1p, onesf, lacc);
    __builtin_amdgcn_s_setprio(0);
  }

  if (nc == 1) {
#pragma unroll
    for (int r = 0; r < 4; ++r) {
      const float inv = 1.0f / lacc[r];
      const int row = t0 + 16 * w + 4 * q_ + r;
      const size_t base = (((size_t)((b << 11) + row)) << 9) + (h << 6) + n_;
#pragma unroll
      for (int nb = 0; nb < 4; ++nb)
        ctxo[base + 16 * nb] = f2bf(ctxa[nb][r] * inv);
    }
  } else {
    const int idx = hb * 72 + pbase_of(ti) + c;
    float* pcb = pc + ((size_t)idx << 12);   // *4096
    float* mlb = ml + ((size_t)idx << 6);    // *64
#pragma unroll
    for (int r = 0; r < 4; ++r) {
      const int row = 16 * w + 4 * q_ + r;
#pragma unroll
      for (int nb = 0; nb < 4; ++nb)
        pcb[(row << 6) + 16 * nb + n_] = ctxa[nb][r];
      if (n_ == 0) mlb[row] = lacc[r];
    }
  }
}

// ---------------------------------------------------------------------------
// K2b: combine chunk partials: out = sum(c_i) / sum(l_i). grid 384 blocks
// (16 hb x 24 multi-chunk tiles, ti 8..31).
// ---------------------------------------------------------------------------
__global__ __launch_bounds__(256) void combine_kernel(
    const float* __restrict__ pc, const float* __restrict__ ml,
    unsigned short* __restrict__ ctxo) {
  const int cb = blockIdx.x;
  const int hb = cb / 24;
  const int ti = 8 + cb % 24;
  const int nc = (ti >> 3) + 1;
  const int h = hb >> 1, b = hb & 1, t0 = ti * 64;
  const int tid = threadIdx.x;
  const int row = tid >> 2, seg = (tid & 3) * 16;
  const int idx0 = hb * 72 + pbase_of(ti);

  float lsum = 0.f;
  float4 a4[4];
#pragma unroll
  for (int j = 0; j < 4; ++j) a4[j] = (float4){0.f, 0.f, 0.f, 0.f};
  for (int c = 0; c < nc; ++c) {
    const int idx = idx0 + c;
    lsum += ml[((size_t)idx << 6) + row];
    const float* cp = pc + ((size_t)idx << 12) + (row << 6) + seg;
#pragma unroll
    for (int j = 0; j < 4; ++j) {
      float4 x = *(const float4*)(cp + 4 * j);
      a4[j].x += x.x; a4[j].y += x.y; a4[j].z += x.z; a4[j].w += x.w;
    }
  }
  const float inv = 1.0f / lsum;
  unsigned short o[16];
#pragma unroll
  for (int j = 0; j < 4; ++j) {
    o[4 * j + 0] = f2bf(a4[j].x * inv);
    o[4 * j + 1] = f2bf(a4[j].y * inv);
    o[4 * j + 2] = f2bf(a4[j].z * inv);
    o[4 * j + 3] = f2bf(a4[j].w * inv);
  }
  unsigned short* dst =
      ctxo + (((size_t)((b << 11) + t0 + row)) << 9) + (h << 6) + seg;
  *(uint4*)dst = *(uint4*)&o[0];
  *(uint4*)(dst + 8) = *(uint4*)&o[8];
}

// ---------------------------------------------------------------------------
// K3: MFMA GEMM, A bf16 [4096][512] @ WT bf16 [Npad][512] + bias, tile 64x64.
// RELU=1: out h1 bf16 [4096][512]. RELU=0: out d_out (dtype per mask), N=388.
// ---------------------------------------------------------------------------
template <int RELU>
__global__ __launch_bounds__(256) void mlp_mfma(
    const unsigned short* __restrict__ A, const unsigned short* __restrict__ WT,
    const void* __restrict__ bias, unsigned short* __restrict__ outBF,
    void* __restrict__ outD, const unsigned int* __restrict__ mask) {
  __shared__ __align__(16) short sA[64][72];
  __shared__ __align__(16) short sW[64][72];
  const int tid = threadIdx.x;
  const int w = tid >> 6, lane = tid & 63;
  const int q_ = lane >> 4, n_ = lane & 15;
  const int row0 = blockIdx.x * 64;
  const int n0 = blockIdx.y * 64;
  const bool isbf = det_bf(mask);

  floatx4 acc[4];
#pragma unroll
  for (int j = 0; j < 4; ++j) acc[j] = (floatx4){0.f, 0.f, 0.f, 0.f};

  for (int k0 = 0; k0 < DM_; k0 += 64) {
#pragma unroll
    for (int it = 0; it < 2; ++it) {
      int idx = tid + it * 256;
      int rr = idx >> 3, cc = (idx & 7) * 8;
      *(uint4*)&sA[rr][cc] = *(const uint4*)(A + (size_t)(row0 + rr) * DM_ + k0 + cc);
      *(uint4*)&sW[rr][cc] = *(const uint4*)(WT + (size_t)(n0 + rr) * DM_ + k0 + cc);
    }
    __syncthreads();
    short8 a0 = *(const short8*)&sA[16 * w + n_][8 * q_];
    short8 a1 = *(const short8*)&sA[16 * w + n_][32 + 8 * q_];
#pragma unroll
    for (int nb = 0; nb < 4; ++nb) {
      short8 b0 = *(const short8*)&sW[16 * nb + n_][8 * q_];
      short8 b1 = *(const short8*)&sW[16 * nb + n_][32 + 8 * q_];
      acc[nb] = MFMA(a0, b0, acc[nb]);
      acc[nb] = MFMA(a1, b1, acc[nb]);
    }
    __syncthreads();
  }

#pragma unroll
  for (int nb = 0; nb < 4; ++nb) {
    const int col = n0 + 16 * nb + n_;
    float bb = 0.f;
    if (RELU || col < EV_) bb = ldf(bias, col, isbf);
#pragma unroll
    for (int r = 0; r < 4; ++r) {
      const int row = row0 + 16 * w + 4 * q_ + r;
      float v = acc[nb][r] + bb;
      if (RELU) {
        outBF[(size_t)row * ED_ + col] = f2bf(fmaxf(v, 0.f));
      } else if (col < EV_) {
        if (isbf) ((unsigned short*)outD)[(size_t)row * EV_ + col] = f2bf(v);
        else      ((float*)outD)[(size_t)row * EV_ + col] = v;
      }
    }
  }
}

// ---------------------------------------------------------------------------
extern "C" void kernel_launch(void* const* d_in, const int* in_sizes, int n_in,
                              void* d_out, int out_size, void* d_ws, size_t ws_size,
                              hipStream_t stream) {
  const void* v  = d_in[0];
  const void* k  = d_in[1];
  const void* q  = d_in[2];
  const unsigned int* mask = (const unsigned int*)d_in[3];
  const void* Wq = d_in[4];
  const void* bq = d_in[5];
  const void* Wk = d_in[6];
  const void* bk = d_in[7];
  const void* Wv = d_in[8];
  const void* bv = d_in[9];
  const void* E  = d_in[10];
  const void* Wo = d_in[11];
  const void* bo = d_in[12];
  const void* Wl = d_in[13];
  const void* bl = d_in[14];

  char* p = (char*)d_ws;
  unsigned short* E_c  = (unsigned short*)p; p += (size_t)H_ * T_ * HD_ * 2;  // 2 MB
  unsigned short* qhb  = (unsigned short*)p; p += (size_t)BT_ * HD_ * 2;
  unsigned short* khb  = (unsigned short*)p; p += (size_t)BT_ * HD_ * 2;
  unsigned short* vtb  = (unsigned short*)p; p += (size_t)BT_ * HD_ * 2;
  unsigned short* WqT  = (unsigned short*)p; p += (size_t)HD_ * DM_ * 2;
  unsigned short* WkT  = (unsigned short*)p; p += (size_t)HD_ * DM_ * 2;
  unsigned short* WvT  = (unsigned short*)p; p += (size_t)HD_ * DM_ * 2;
  unsigned short* WoT  = (unsigned short*)p; p += (size_t)ED_ * DM_ * 2;
  unsigned short* WlT  = (unsigned short*)p; p += (size_t)448 * DM_ * 2;
  unsigned short* ctxb = (unsigned short*)p; p += (size_t)BT_ * DM_ * 2;      // 4 MB
  unsigned short* h1b  = (unsigned short*)p; p += (size_t)BT_ * ED_ * 2;      // 4 MB
  float* pc = (float*)p; p += (size_t)16 * 72 * 4096 * 4;                     // 18.9 MB
  float* ml = (float*)p; p += (size_t)16 * 72 * 64 * 4;                       // 0.3 MB

  prep_kernel<<<dim3(1312), 256, 0, stream>>>(
      E, Wq, Wk, Wv, Wo, Wl, mask, E_c, WqT, WkT, WvT, WoT, WlT);
  gemm_proj<<<dim3(BT_ / 64, 3), 256, 0, stream>>>(
      q, k, v, WqT, WkT, WvT, bq, bk, bv, mask, qhb, khb, vtb);
  attn_kernel<<<dim3(1280), 256, 0, stream>>>(qhb, khb, vtb, E_c, ctxb, pc, ml);
  combine_kernel<<<dim3(384), 256, 0, stream>>>(pc, ml, ctxb);
  mlp_mfma<1><<<dim3(BT_ / 64, ED_ / 64), 256, 0, stream>>>(
      ctxb, WoT, bo, h1b, nullptr, mask);
  mlp_mfma<0><<<dim3(BT_ / 64, 448 / 64), 256, 0, stream>>>(
      h1b, WlT, bl, nullptr, d_out, mask);
}

// Round 10
// 203.530 us; speedup vs baseline: 1.1592x; 1.0011x over previous
//
#include <hip/hip_runtime.h>
#include <hip/hip_bf16.h>

// Music-Transformer RelativeGlobalAttention, MI355X round 17.
// B=2, T=2048, D=512, H=8, hd=64, ED=512, EV=388. fp32 I/O (runtime-detected
// via mask[0] bit pattern), bf16 MFMA compute, fp32 accumulation.
// R17: merge R15 (1 barrier/step) with R16 (counted vmcnt, E panel ring).
// R16 post-mortem: counted vmcnt alone was neutral -- the drain wasn't the
// cost, but R16's SECOND barrier/step ate the E-ring savings. R17 = ONE
// barrier + ONE counted vmcnt(2) per step: with pinned issue order K->E->V,
// step-top vmcnt(2) retires exactly {V(s-1), K(s), E(s)} (all this step's
// inputs) while V(s) stays in flight until its deferred PV next step.
// vmcnt(0) only in the epilogue. Whole step is one scheduling region (QK,
// QE, deferred PV, skew can interleave). Mod-3 -> wrap counters.

#define B_ 2
#define T_ 2048
#define DM_ 512
#define H_ 8
#define HD_ 64
#define ED_ 512
#define EV_ 388
#define BT_ (B_ * T_)

typedef __attribute__((ext_vector_type(8))) short short8;
typedef __attribute__((ext_vector_type(4))) float floatx4;

#define MFMA(a, b, c) __builtin_amdgcn_mfma_f32_16x16x32_bf16((a), (b), (c), 0, 0, 0)

__device__ __forceinline__ float bfs(unsigned short s) {
  union { unsigned int i; float f; } v; v.i = ((unsigned int)s) << 16; return v.f;
}
__device__ __forceinline__ unsigned short f2bf(float f) {
  __hip_bfloat16 h = __float2bfloat16(f);
  union { __hip_bfloat16 h; unsigned short u; } v; v.h = h; return v.u;
}
__device__ __forceinline__ float ldf(const void* p, int i, bool isbf) {
  return isbf ? bfs(((const unsigned short*)p)[i]) : ((const float*)p)[i];
}
__device__ __forceinline__ bool det_bf(const unsigned int* mask) {
  return mask[0] != 0x3F800000u;  // fp32 1.0f word; bf16-packed differs
}
__device__ __forceinline__ void gl_lds16(const unsigned short* g, void* l) {
  __builtin_amdgcn_global_load_lds(
      (const __attribute__((address_space(1))) void*)g,
      (__attribute__((address_space(3))) void*)l, 16, 0, 0);
}

// ---------------------------------------------------------------------------
// K0 prep: [0,1024) E->bf16 copy/convert; [1024,1312) weight transposes
// src [512][N] -> dst [Npad][512] bf16, zero-padded rows.
// ---------------------------------------------------------------------------
__global__ __launch_bounds__(256) void prep_kernel(
    const void* __restrict__ E, const void* __restrict__ Wq,
    const void* __restrict__ Wk, const void* __restrict__ Wv,
    const void* __restrict__ Wo, const void* __restrict__ Wl,
    const unsigned int* __restrict__ mask,
    unsigned short* __restrict__ E_c, unsigned short* __restrict__ WqT,
    unsigned short* __restrict__ WkT, unsigned short* __restrict__ WvT,
    unsigned short* __restrict__ WoT, unsigned short* __restrict__ WlT) {
  const bool isbf = det_bf(mask);
  const int tid = threadIdx.x;
  int bi = blockIdx.x;
  if (bi < 1024) {
    const int i0 = (bi * 256 + tid) * 4;
    if (isbf) {
      *(uint2*)&E_c[i0] = *(const uint2*)((const unsigned short*)E + i0);
    } else {
      float4 f = *(const float4*)((const float*)E + i0);
      unsigned short p[4] = {f2bf(f.x), f2bf(f.y), f2bf(f.z), f2bf(f.w)};
      *(uint2*)&E_c[i0] = *(uint2*)p;
    }
    return;
  }
  bi -= 1024;
  const void* src; unsigned short* dst; int N, nb;
  if (bi < 16)       { src = Wq; dst = WqT; N = 64;  nb = bi; }
  else if (bi < 32)  { src = Wk; dst = WkT; N = 64;  nb = bi - 16; }
  else if (bi < 48)  { src = Wv; dst = WvT; N = 64;  nb = bi - 32; }
  else if (bi < 176) { src = Wo; dst = WoT; N = 512; nb = bi - 48; }
  else               { src = Wl; dst = WlT; N = 388; nb = bi - 176; }
  const int n = nb * 4 + (tid >> 6);
  const int k0 = (tid & 63) * 8;
  unsigned short vv[8];
#pragma unroll
  for (int j = 0; j < 8; ++j) {
    if (n >= N) vv[j] = 0;
    else if (isbf) vv[j] = ((const unsigned short*)src)[(size_t)(k0 + j) * N + n];
    else vv[j] = f2bf(((const float*)src)[(size_t)(k0 + j) * N + n]);
  }
  *(uint4*)&dst[(size_t)n * DM_ + k0] = *(uint4*)vv;
}

// ---------------------------------------------------------------------------
// K1: projections. grid (64, 3), tile 64x64, block 256 (4 waves).
// sel 0/1 -> qh/kh row-major bf16 [4096][64]; sel 2 -> vt [B][64][2048] bf16.
// ---------------------------------------------------------------------------
__global__ __launch_bounds__(256) void gemm_proj(
    const void* __restrict__ xq, const void* __restrict__ xk,
    const void* __restrict__ xv,
    const unsigned short* __restrict__ WqT, const unsigned short* __restrict__ WkT,
    const unsigned short* __restrict__ WvT,
    const void* __restrict__ bq, const void* __restrict__ bk,
    const void* __restrict__ bv, const unsigned int* __restrict__ mask,
    unsigned short* __restrict__ oq, unsigned short* __restrict__ ok,
    unsigned short* __restrict__ ovt) {
  __shared__ __align__(16) short sA[64][72];
  __shared__ __align__(16) short sW[64][72];
  const int sel = blockIdx.y;
  const void* x = (sel == 0) ? xq : (sel == 1) ? xk : xv;
  const unsigned short* WT = (sel == 0) ? WqT : (sel == 1) ? WkT : WvT;
  const void* bias = (sel == 0) ? bq : (sel == 1) ? bk : bv;
  const bool isbf = det_bf(mask);

  const int tid = threadIdx.x;
  const int w = tid >> 6, lane = tid & 63;
  const int q_ = lane >> 4, n_ = lane & 15;
  const int row0 = blockIdx.x * 64;

  floatx4 acc[4];
#pragma unroll
  for (int j = 0; j < 4; ++j) acc[j] = (floatx4){0.f, 0.f, 0.f, 0.f};

  for (int k0 = 0; k0 < DM_; k0 += 64) {
    if (isbf) {
#pragma unroll
      for (int it = 0; it < 2; ++it) {
        int idx = tid + it * 256;
        int rr = idx >> 3, cc = (idx & 7) * 8;
        *(uint4*)&sA[rr][cc] =
            *(const uint4*)((const unsigned short*)x + (size_t)(row0 + rr) * DM_ + k0 + cc);
      }
    } else {
#pragma unroll
      for (int it = 0; it < 4; ++it) {
        int idx = tid + it * 256;
        int rr = idx >> 4, cc = (idx & 15) * 4;
        float4 f = *(const float4*)((const float*)x + (size_t)(row0 + rr) * DM_ + k0 + cc);
        unsigned short p[4] = {f2bf(f.x), f2bf(f.y), f2bf(f.z), f2bf(f.w)};
        *(uint2*)&sA[rr][cc] = *(uint2*)p;
      }
    }
#pragma unroll
    for (int it = 0; it < 2; ++it) {
      int idx = tid + it * 256;
      int rr = idx >> 3, cc = (idx & 7) * 8;
      *(uint4*)&sW[rr][cc] = *(const uint4*)(WT + (size_t)rr * DM_ + k0 + cc);
    }
    __syncthreads();
    short8 a0 = *(const short8*)&sA[16 * w + n_][8 * q_];
    short8 a1 = *(const short8*)&sA[16 * w + n_][32 + 8 * q_];
#pragma unroll
    for (int nb = 0; nb < 4; ++nb) {
      short8 b0 = *(const short8*)&sW[16 * nb + n_][8 * q_];
      short8 b1 = *(const short8*)&sW[16 * nb + n_][32 + 8 * q_];
      acc[nb] = MFMA(a0, b0, acc[nb]);
      acc[nb] = MFMA(a1, b1, acc[nb]);
    }
    __syncthreads();
  }

#pragma unroll
  for (int nb = 0; nb < 4; ++nb) {
    const int col = 16 * nb + n_;
    const float bb = ldf(bias, col, isbf);
#pragma unroll
    for (int r = 0; r < 4; ++r) {
      int row = row0 + 16 * w + 4 * q_ + r;
      unsigned short val = f2bf(acc[nb][r] + bb);
      if (sel < 2) {
        unsigned short* o = (sel == 0) ? oq : ok;
        o[(size_t)row * HD_ + col] = val;
      } else {
        int b = row >> 11, s = row & 2047;
        ovt[(((size_t)(b * HD_ + col)) << 11) + s] = val;
      }
    }
  }
}

// ---------------------------------------------------------------------------
// Chunk mapping (R7 table): 80 chunks/hb, grid 1280; hb = id&15,
// rem = 79 - id/16 (LONG chunks get the lowest blockIdx -> dispatched first).
// ti 0..7 -> 1 chunk; 8..15 -> 2; 16..23 -> 3; 24..31 -> 4. Max 8 K-steps.
// Multi-chunk tiles (ti>=8) store partials at slot hb*72 + pbase(ti) + c.
// ---------------------------------------------------------------------------
__device__ __forceinline__ int pbase_of(int ti) {
  return (ti < 16) ? (ti - 8) * 2 : (ti < 24) ? 16 + (ti - 16) * 3
                                              : 40 + (ti - 24) * 4;
}

// ---------------------------------------------------------------------------
// K2: fused causal attention. grid 1280, 4 waves/block, 16-row q-strips.
// K double-buffered, V + E-panel triple-buffered rings, all DMA-staged with
// pre-swizzled source. ONE barrier + ONE counted vmcnt(2) per step (pinned
// issue order K->E->V; V(s) rides through step s, consumed by deferred PV
// in step s+1). vmcnt(0) only in the epilogue. Deferred PV (T15).
// ---------------------------------------------------------------------------
__global__ __launch_bounds__(256, 2) void attn_kernel(
    const unsigned short* __restrict__ qh, const unsigned short* __restrict__ kh,
    const unsigned short* __restrict__ vt, const unsigned short* __restrict__ E,
    unsigned short* __restrict__ ctxo, float* __restrict__ pc,
    float* __restrict__ ml) {
  __shared__ __align__(16) short sK[2][64][64];    // 16 KB
  __shared__ __align__(16) short sVT[3][64][64];   // 24 KB (ring)
  __shared__ __align__(16) short sE3[3][64][64];   // 24 KB (panel ring)
  __shared__ __align__(16) short sP[64][64];       // 8 KB; wave w rows [16w,16w+16)

  const int id = blockIdx.x;
  const int hb = id & 15;        // all chunks of hb share id%8 -> same XCD
  const int rem = 79 - (id >> 4);  // long chunks first in dispatch order
  int ti, c, nc;
  if (rem < 8)       { ti = rem;                 c = 0;            nc = 1; }
  else if (rem < 24) { ti = 8 + ((rem - 8) >> 1);  c = (rem - 8) & 1;  nc = 2; }
  else if (rem < 48) { ti = 16 + (rem - 24) / 3;   c = (rem - 24) % 3; nc = 3; }
  else               { ti = 24 + ((rem - 48) >> 2); c = (rem - 48) & 3; nc = 4; }
  const int nsteps = ti + 1;
  const int klo = (c * nsteps) / nc;
  const int khi = ((c + 1) * nsteps) / nc;

  const int h = hb >> 1, b = hb & 1;
  const int t0 = ti * 64;

  const int tid = threadIdx.x;
  const int w = tid >> 6, lane = tid & 63;
  const int q_ = lane >> 4, n_ = lane & 15;

  const int trow = t0 + 16 * w + n_;
  const unsigned short* qp = qh + (((size_t)((b << 11) + trow)) << 6) + (q_ << 3);
  const short8 qa0 = *(const short8*)qp;
  const short8 qa1 = *(const short8*)(qp + 32);

  short8 onesf;
#pragma unroll
  for (int j = 0; j < 8; ++j) onesf[j] = (short)0x3F80;  // bf16 1.0

  floatx4 ctxa[4];
#pragma unroll
  for (int nb = 0; nb < 4; ++nb) ctxa[nb] = (floatx4){0.f, 0.f, 0.f, 0.f};
  floatx4 lacc = (floatx4){0.f, 0.f, 0.f, 0.f};

  const unsigned short* eb = E + ((size_t)h << 17);
  const unsigned short* kbase = kh + (((size_t)(b << 11)) << 6);
  const unsigned short* vbase = vt + (((size_t)(b << 6)) << 11);

  // DMA staging geometry. Each gl_lds16 covers 8 rows x 8 chunks (64 lanes x
  // 16B, LDS dest linear). Source col-chunk pre-XOR'd with row&7 so the
  // linear LDS dest ends up XOR-swizzled.
  const int lrow8 = lane >> 3;                     // 0..7
  const int lch = ((lane & 7) ^ lrow8) << 3;       // swizzled source col
  const int rK0 = 8 * w + lrow8;
  // Swizzled read cols (logical chunk q_ / q_+4 of a row with row%8 == n_&7):
  const int c0s = ((q_ ^ (n_ & 7)) << 3);
  const int c1s = (((q_ | 4) ^ (n_ & 7)) << 3);

// Issue-order-pinned staging groups (vmcnt FIFO arithmetic depends on order):
#define STAGE_K(kbuf, s0v)                                                     \
  {                                                                            \
    const unsigned short* gK =                                                 \
        kbase + (((size_t)((s0v) + rK0)) << 6) + lch;                          \
    gl_lds16(gK, (void*)&sK[kbuf][8 * w][0]);                                  \
    gl_lds16(gK + (32 << 6), (void*)(&sK[kbuf][8 * w][0] + 32 * 64));          \
  }
#define STAGE_E(slot, panel)                                                   \
  {                                                                            \
    _Pragma("unroll") for (int j = 0; j < 2; ++j) {                            \
      int gr = 64 * (panel) + 16 * w + 8 * j + lrow8;                          \
      if (gr > T_ - 1) gr = T_ - 1; /* clamped rows are masked s>t */          \
      gl_lds16(eb + ((size_t)gr << 6) + lch,                                   \
               (void*)&sE3[slot][16 * w + 8 * j][0]);                          \
    }                                                                          \
  }
#define STAGE_V(vbuf, s0v)                                                     \
  {                                                                            \
    const unsigned short* gV =                                                 \
        vbase + (((size_t)rK0) << 11) + (s0v) + lch;                           \
    gl_lds16(gV, (void*)&sVT[vbuf][8 * w][0]);                                 \
    gl_lds16(gV + (32 << 11), (void*)(&sVT[vbuf][8 * w][0] + 32 * 64));        \
  }

  // Prologue (issue order K, E, E, V -> 8 outstanding; the loop's counted
  // waits cover the retirement).
  const int p0 = 31 + klo - ti;         // first window panel (>= 0)
  {
    STAGE_K(0, klo * 64);
    __builtin_amdgcn_sched_barrier(0);
    STAGE_E(p0 % 3, p0);
    STAGE_E((p0 + 1) % 3, p0 + 1);
    __builtin_amdgcn_sched_barrier(0);
    STAGE_V(0, klo * 64);
  }

  short8 pa0p = {0, 0, 0, 0, 0, 0, 0, 0};  // deferred-PV fragments,
  short8 pa1p = {0, 0, 0, 0, 0, 0, 0, 0};  // carried across the barrier

  // Wrap counters (avoid mod-3 magic-mul):
  int vcur = 0;                 // V ring slot of this step
  int slotA = p0 % 3;           // E panel slot: window rows 0..63
  int slotB = slotA + 1 == 3 ? 0 : slotA + 1;  // window rows 64..127

  for (int kt = klo; kt < khi; ++kt) {
    const int ph = (kt - klo) & 1;       // K double-buffer phase
    const int s0 = kt * 64;
    const int slotC = slotB + 1 == 3 ? 0 : slotB + 1;  // staging target
    const int vnext = vcur + 1 == 3 ? 0 : vcur + 1;
    const int vprev = vcur == 0 ? 2 : vcur - 1;

    // ---- step top: retire {V(s-1), K(s), E(s)}; V(s) stays in flight ----
    asm volatile("s_waitcnt vmcnt(2)" ::: "memory");
    __builtin_amdgcn_sched_barrier(0);
    __builtin_amdgcn_s_barrier();
    __builtin_amdgcn_sched_barrier(0);

    // Issue next step's staging (K -> E -> V, order pinned).
    if (kt + 1 < khi) {
      STAGE_K(ph ^ 1, s0 + 64);
      __builtin_amdgcn_sched_barrier(0);
      STAGE_E(slotC, p0 + (kt - klo) + 2);
      __builtin_amdgcn_sched_barrier(0);
      STAGE_V(vnext, s0 + 64);
    }

    // ---- QK MFMA from LDS K ----
    floatx4 qk[4];
    __builtin_amdgcn_s_setprio(1);
#pragma unroll
    for (int nb = 0; nb < 4; ++nb) {
      short8 kb0 = *(const short8*)&sK[ph][16 * nb + n_][c0s];
      short8 kb1 = *(const short8*)&sK[ph][16 * nb + n_][c1s];
      qk[nb] = (floatx4){0.f, 0.f, 0.f, 0.f};
      qk[nb] = MFMA(qa0, kb0, qk[nb]);
      qk[nb] = MFMA(qa1, kb1, qk[nb]);
    }
    // ---- QE MFMA from E panel ring ----
    floatx4 qe[5];
#pragma unroll
    for (int f = 0; f < 5; ++f) {
      const int row16 = 16 * (3 - w + f);          // 0..112, 16-aligned
      const short* ep = (row16 < 64) ? &sE3[slotA][row16 + n_][0]
                                     : &sE3[slotB][row16 - 64 + n_][0];
      short8 eb0 = *(const short8*)(ep + c0s);
      short8 eb1 = *(const short8*)(ep + c1s);
      qe[f] = (floatx4){0.f, 0.f, 0.f, 0.f};
      qe[f] = MFMA(qa0, eb0, qe[f]);
      qe[f] = MFMA(qa1, eb1, qe[f]);
    }
    // ---- deferred PV + l for step kt-1 (V(s-1) retired at step top;
    //      independent of QK/QE/skew -> fills their latency shadow) ----
    if (kt > klo) {
#pragma unroll
      for (int nb = 0; nb < 4; ++nb) {
        short8 v0 = *(const short8*)&sVT[vprev][16 * nb + n_][c0s];
        short8 v1 = *(const short8*)&sVT[vprev][16 * nb + n_][c1s];
        ctxa[nb] = MFMA(pa0p, v0, ctxa[nb]);
        ctxa[nb] = MFMA(pa1p, v1, ctxa[nb]);
      }
      lacc = MFMA(pa0p, onesf, lacc);
      lacc = MFMA(pa1p, onesf, lacc);
    }
    __builtin_amdgcn_s_setprio(0);

    // ---- skew diagonal (16 bpermute, source-side frag select) + exp + sP --
    const bool diag = (kt == ti);
#pragma unroll
    for (int r = 0; r < 4; ++r) {
      const int t = 4 * q_ + r;
      const int ba = ((q_ << 4) | ((n_ - t + 15) & 15)) << 2;
      const int nd = (n_ + t + 1) & 15;   // dest lane (same q_) pulling from us
      const bool hi = nd > t;             // dest picks qe[mb+1] iff its n_ > t
      const int swr = (t & 7) << 3;       // sP row-swizzle term
#pragma unroll
      for (int mb = 0; mb < 4; ++mb) {
        float merged = hi ? qe[mb + 1][r] : qe[mb][r];
        float g = __int_as_float(
            __builtin_amdgcn_ds_bpermute(ba, __float_as_int(merged)));
        float sv = qk[mb][r] + g;
        if (diag && (16 * mb + n_ > 16 * w + t)) sv = -1.0e30f;  // exp -> 0
        // exp(sv*0.125) == exp2(sv * 0.125*log2(e))
        sP[16 * w + t][(16 * mb + n_) ^ swr] =
            (short)f2bf(exp2f(sv * 0.18033688011f));
      }
    }

    // ---- read own P strip into regs for NEXT step's deferred PV ----
    pa0p = *(const short8*)&sP[16 * w + n_][c0s];
    pa1p = *(const short8*)&sP[16 * w + n_][c1s];

    // Advance ring counters.
    vcur = vnext;
    slotA = slotB;
    slotB = slotC;
  }
#undef STAGE_K
#undef STAGE_E
#undef STAGE_V

  // ---- epilogue: V(khi-1) fully retired, then last PV + l ----
  asm volatile("s_waitcnt vmcnt(0)" ::: "memory");
  __builtin_amdgcn_sched_barrier(0);
  __builtin_amdgcn_s_barrier();
  __builtin_amdgcn_sched_barrier(0);
  {
    const int vlast = vcur == 0 ? 2 : vcur - 1;  // slot of step khi-1
    __builtin_amdgcn_s_setprio(1);
#pragma unroll
    for (int nb = 0; nb < 4; ++nb) {
      short8 v0 = *(const short8*)&sVT[vlast][16 * nb + n_][c0s];
      short8 v1 = *(const short8*)&sVT[vlast][16 * nb + n_][c1s];
      ctxa[nb] = MFMA(pa0p, v0, ctxa[nb]);
      ctxa[nb] = MFMA(pa1p, v1, ctxa[nb]);
    }
    lacc = MFMA(pa0p, onesf, lacc);
    lacc = MFMA(pa1p, onesf, lacc);
    __builtin_amdgcn_s_setprio(0);
  }

  if (nc == 1) {
#pragma unroll
    for (int r = 0; r < 4; ++r) {
      const float inv = 1.0f / lacc[r];
      const int row = t0 + 16 * w + 4 * q_ + r;
      const size_t base = (((size_t)((b << 11) + row)) << 9) + (h << 6) + n_;
#pragma unroll
      for (int nb = 0; nb < 4; ++nb)
        ctxo[base + 16 * nb] = f2bf(ctxa[nb][r] * inv);
    }
  } else {
    const int idx = hb * 72 + pbase_of(ti) + c;
    float* pcb = pc + ((size_t)idx << 12);   // *4096
    float* mlb = ml + ((size_t)idx << 6);    // *64
#pragma unroll
    for (int r = 0; r < 4; ++r) {
      const int row = 16 * w + 4 * q_ + r;
#pragma unroll
      for (int nb = 0; nb < 4; ++nb)
        pcb[(row << 6) + 16 * nb + n_] = ctxa[nb][r];
      if (n_ == 0) mlb[row] = lacc[r];
    }
  }
}

// ---------------------------------------------------------------------------
// K2b: combine chunk partials: out = sum(c_i) / sum(l_i). grid 384 blocks
// (16 hb x 24 multi-chunk tiles, ti 8..31).
// ---------------------------------------------------------------------------
__global__ __launch_bounds__(256) void combine_kernel(
    const float* __restrict__ pc, const float* __restrict__ ml,
    unsigned short* __restrict__ ctxo) {
  const int cb = blockIdx.x;
  const int hb = cb / 24;
  const int ti = 8 + cb % 24;
  const int nc = (ti >> 3) + 1;
  const int h = hb >> 1, b = hb & 1, t0 = ti * 64;
  const int tid = threadIdx.x;
  const int row = tid >> 2, seg = (tid & 3) * 16;
  const int idx0 = hb * 72 + pbase_of(ti);

  float lsum = 0.f;
  float4 a4[4];
#pragma unroll
  for (int j = 0; j < 4; ++j) a4[j] = (float4){0.f, 0.f, 0.f, 0.f};
  for (int c = 0; c < nc; ++c) {
    const int idx = idx0 + c;
    lsum += ml[((size_t)idx << 6) + row];
    const float* cp = pc + ((size_t)idx << 12) + (row << 6) + seg;
#pragma unroll
    for (int j = 0; j < 4; ++j) {
      float4 x = *(const float4*)(cp + 4 * j);
      a4[j].x += x.x; a4[j].y += x.y; a4[j].z += x.z; a4[j].w += x.w;
    }
  }
  const float inv = 1.0f / lsum;
  unsigned short o[16];
#pragma unroll
  for (int j = 0; j < 4; ++j) {
    o[4 * j + 0] = f2bf(a4[j].x * inv);
    o[4 * j + 1] = f2bf(a4[j].y * inv);
    o[4 * j + 2] = f2bf(a4[j].z * inv);
    o[4 * j + 3] = f2bf(a4[j].w * inv);
  }
  unsigned short* dst =
      ctxo + (((size_t)((b << 11) + t0 + row)) << 9) + (h << 6) + seg;
  *(uint4*)dst = *(uint4*)&o[0];
  *(uint4*)(dst + 8) = *(uint4*)&o[8];
}

// ---------------------------------------------------------------------------
// K3: MFMA GEMM, A bf16 [4096][512] @ WT bf16 [Npad][512] + bias, tile 64x64.
// RELU=1: out h1 bf16 [4096][512]. RELU=0: out d_out (dtype per mask), N=388.
// ---------------------------------------------------------------------------
template <int RELU>
__global__ __launch_bounds__(256) void mlp_mfma(
    const unsigned short* __restrict__ A, const unsigned short* __restrict__ WT,
    const void* __restrict__ bias, unsigned short* __restrict__ outBF,
    void* __restrict__ outD, const unsigned int* __restrict__ mask) {
  __shared__ __align__(16) short sA[64][72];
  __shared__ __align__(16) short sW[64][72];
  const int tid = threadIdx.x;
  const int w = tid >> 6, lane = tid & 63;
  const int q_ = lane >> 4, n_ = lane & 15;
  const int row0 = blockIdx.x * 64;
  const int n0 = blockIdx.y * 64;
  const bool isbf = det_bf(mask);

  floatx4 acc[4];
#pragma unroll
  for (int j = 0; j < 4; ++j) acc[j] = (floatx4){0.f, 0.f, 0.f, 0.f};

  for (int k0 = 0; k0 < DM_; k0 += 64) {
#pragma unroll
    for (int it = 0; it < 2; ++it) {
      int idx = tid + it * 256;
      int rr = idx >> 3, cc = (idx & 7) * 8;
      *(uint4*)&sA[rr][cc] = *(const uint4*)(A + (size_t)(row0 + rr) * DM_ + k0 + cc);
      *(uint4*)&sW[rr][cc] = *(const uint4*)(WT + (size_t)(n0 + rr) * DM_ + k0 + cc);
    }
    __syncthreads();
    short8 a0 = *(const short8*)&sA[16 * w + n_][8 * q_];
    short8 a1 = *(const short8*)&sA[16 * w + n_][32 + 8 * q_];
#pragma unroll
    for (int nb = 0; nb < 4; ++nb) {
      short8 b0 = *(const short8*)&sW[16 * nb + n_][8 * q_];
      short8 b1 = *(const short8*)&sW[16 * nb + n_][32 + 8 * q_];
      acc[nb] = MFMA(a0, b0, acc[nb]);
      acc[nb] = MFMA(a1, b1, acc[nb]);
    }
    __syncthreads();
  }

#pragma unroll
  for (int nb = 0; nb < 4; ++nb) {
    const int col = n0 + 16 * nb + n_;
    float bb = 0.f;
    if (RELU || col < EV_) bb = ldf(bias, col, isbf);
#pragma unroll
    for (int r = 0; r < 4; ++r) {
      const int row = row0 + 16 * w + 4 * q_ + r;
      float v = acc[nb][r] + bb;
      if (RELU) {
        outBF[(size_t)row * ED_ + col] = f2bf(fmaxf(v, 0.f));
      } else if (col < EV_) {
        if (isbf) ((unsigned short*)outD)[(size_t)row * EV_ + col] = f2bf(v);
        else      ((float*)outD)[(size_t)row * EV_ + col] = v;
      }
    }
  }
}

// ---------------------------------------------------------------------------
extern "C" void kernel_launch(void* const* d_in, const int* in_sizes, int n_in,
                              void* d_out, int out_size, void* d_ws, size_t ws_size,
                              hipStream_t stream) {
  const void* v  = d_in[0];
  const void* k  = d_in[1];
  const void* q  = d_in[2];
  const unsigned int* mask = (const unsigned int*)d_in[3];
  const void* Wq = d_in[4];
  const void* bq = d_in[5];
  const void* Wk = d_in[6];
  const void* bk = d_in[7];
  const void* Wv = d_in[8];
  const void* bv = d_in[9];
  const void* E  = d_in[10];
  const void* Wo = d_in[11];
  const void* bo = d_in[12];
  const void* Wl = d_in[13];
  const void* bl = d_in[14];

  char* p = (char*)d_ws;
  unsigned short* E_c  = (unsigned short*)p; p += (size_t)H_ * T_ * HD_ * 2;  // 2 MB
  unsigned short* qhb  = (unsigned short*)p; p += (size_t)BT_ * HD_ * 2;
  unsigned short* khb  = (unsigned short*)p; p += (size_t)BT_ * HD_ * 2;
  unsigned short* vtb  = (unsigned short*)p; p += (size_t)BT_ * HD_ * 2;
  unsigned short* WqT  = (unsigned short*)p; p += (size_t)HD_ * DM_ * 2;
  unsigned short* WkT  = (unsigned short*)p; p += (size_t)HD_ * DM_ * 2;
  unsigned short* WvT  = (unsigned short*)p; p += (size_t)HD_ * DM_ * 2;
  unsigned short* WoT  = (unsigned short*)p; p += (size_t)ED_ * DM_ * 2;
  unsigned short* WlT  = (unsigned short*)p; p += (size_t)448 * DM_ * 2;
  unsigned short* ctxb = (unsigned short*)p; p += (size_t)BT_ * DM_ * 2;      // 4 MB
  unsigned short* h1b  = (unsigned short*)p; p += (size_t)BT_ * ED_ * 2;      // 4 MB
  float* pc = (float*)p; p += (size_t)16 * 72 * 4096 * 4;                     // 18.9 MB
  float* ml = (float*)p; p += (size_t)16 * 72 * 64 * 4;                       // 0.3 MB

  prep_kernel<<<dim3(1312), 256, 0, stream>>>(
      E, Wq, Wk, Wv, Wo, Wl, mask, E_c, WqT, WkT, WvT, WoT, WlT);
  gemm_proj<<<dim3(BT_ / 64, 3), 256, 0, stream>>>(
      q, k, v, WqT, WkT, WvT, bq, bk, bv, mask, qhb, khb, vtb);
  attn_kernel<<<dim3(1280), 256, 0, stream>>>(qhb, khb, vtb, E_c, ctxb, pc, ml);
  combine_kernel<<<dim3(384), 256, 0, stream>>>(pc, ml, ctxb);
  mlp_mfma<1><<<dim3(BT_ / 64, ED_ / 64), 256, 0, stream>>>(
      ctxb, WoT, bo, h1b, nullptr, mask);
  mlp_mfma<0><<<dim3(BT_ / 64, 448 / 64), 256, 0, stream>>>(
      h1b, WlT, bl, nullptr, d_out, mask);
}

// Round 11
// 197.759 us; speedup vs baseline: 1.1930x; 1.0292x over previous
//
#include <hip/hip_runtime.h>
#include <hip/hip_bf16.h>

// Music-Transformer RelativeGlobalAttention, MI355X round 18.
// B=2, T=2048, D=512, H=8, hd=64, ED=512, EV=388. fp32 I/O (runtime-detected
// via mask[0] bit pattern), bf16 MFMA compute, fp32 accumulation.
// R18: attn kept at R17 (best: 52.8us; 1 barrier + counted vmcnt(2)/step,
// K/V/E DMA rings, deferred PV). This round targets the INVISIBLE remainder
// (total-attn = 150us stable across 9 rounds; top-5 only shows attn, so each
// small kernel is <52us but they may sum to 40-80us): mlp_mfma rewritten
// with the attn-proven DMA pipeline -- global_load_lds width-16 staging
// (Common-mistake #1; m193 +67%), XOR-swizzled LDS via pre-swizzled source,
// double-buffer, ONE s_barrier + vmcnt(0) per K-step, setprio on MFMA.
// LDS 32KB -> 5 blocks/CU. If total doesn't move, the remainder is harness
// overhead and the pipeline is at its practical plateau.

#define B_ 2
#define T_ 2048
#define DM_ 512
#define H_ 8
#define HD_ 64
#define ED_ 512
#define EV_ 388
#define BT_ (B_ * T_)

typedef __attribute__((ext_vector_type(8))) short short8;
typedef __attribute__((ext_vector_type(4))) float floatx4;

#define MFMA(a, b, c) __builtin_amdgcn_mfma_f32_16x16x32_bf16((a), (b), (c), 0, 0, 0)

__device__ __forceinline__ float bfs(unsigned short s) {
  union { unsigned int i; float f; } v; v.i = ((unsigned int)s) << 16; return v.f;
}
__device__ __forceinline__ unsigned short f2bf(float f) {
  __hip_bfloat16 h = __float2bfloat16(f);
  union { __hip_bfloat16 h; unsigned short u; } v; v.h = h; return v.u;
}
__device__ __forceinline__ float ldf(const void* p, int i, bool isbf) {
  return isbf ? bfs(((const unsigned short*)p)[i]) : ((const float*)p)[i];
}
__device__ __forceinline__ bool det_bf(const unsigned int* mask) {
  return mask[0] != 0x3F800000u;  // fp32 1.0f word; bf16-packed differs
}
__device__ __forceinline__ void gl_lds16(const unsigned short* g, void* l) {
  __builtin_amdgcn_global_load_lds(
      (const __attribute__((address_space(1))) void*)g,
      (__attribute__((address_space(3))) void*)l, 16, 0, 0);
}

// ---------------------------------------------------------------------------
// K0 prep: [0,1024) E->bf16 copy/convert; [1024,1312) weight transposes
// src [512][N] -> dst [Npad][512] bf16, zero-padded rows.
// ---------------------------------------------------------------------------
__global__ __launch_bounds__(256) void prep_kernel(
    const void* __restrict__ E, const void* __restrict__ Wq,
    const void* __restrict__ Wk, const void* __restrict__ Wv,
    const void* __restrict__ Wo, const void* __restrict__ Wl,
    const unsigned int* __restrict__ mask,
    unsigned short* __restrict__ E_c, unsigned short* __restrict__ WqT,
    unsigned short* __restrict__ WkT, unsigned short* __restrict__ WvT,
    unsigned short* __restrict__ WoT, unsigned short* __restrict__ WlT) {
  const bool isbf = det_bf(mask);
  const int tid = threadIdx.x;
  int bi = blockIdx.x;
  if (bi < 1024) {
    const int i0 = (bi * 256 + tid) * 4;
    if (isbf) {
      *(uint2*)&E_c[i0] = *(const uint2*)((const unsigned short*)E + i0);
    } else {
      float4 f = *(const float4*)((const float*)E + i0);
      unsigned short p[4] = {f2bf(f.x), f2bf(f.y), f2bf(f.z), f2bf(f.w)};
      *(uint2*)&E_c[i0] = *(uint2*)p;
    }
    return;
  }
  bi -= 1024;
  const void* src; unsigned short* dst; int N, nb;
  if (bi < 16)       { src = Wq; dst = WqT; N = 64;  nb = bi; }
  else if (bi < 32)  { src = Wk; dst = WkT; N = 64;  nb = bi - 16; }
  else if (bi < 48)  { src = Wv; dst = WvT; N = 64;  nb = bi - 32; }
  else if (bi < 176) { src = Wo; dst = WoT; N = 512; nb = bi - 48; }
  else               { src = Wl; dst = WlT; N = 388; nb = bi - 176; }
  const int n = nb * 4 + (tid >> 6);
  const int k0 = (tid & 63) * 8;
  unsigned short vv[8];
#pragma unroll
  for (int j = 0; j < 8; ++j) {
    if (n >= N) vv[j] = 0;
    else if (isbf) vv[j] = ((const unsigned short*)src)[(size_t)(k0 + j) * N + n];
    else vv[j] = f2bf(((const float*)src)[(size_t)(k0 + j) * N + n]);
  }
  *(uint4*)&dst[(size_t)n * DM_ + k0] = *(uint4*)vv;
}

// ---------------------------------------------------------------------------
// K1: projections. grid (64, 3), tile 64x64, block 256 (4 waves).
// sel 0/1 -> qh/kh row-major bf16 [4096][64]; sel 2 -> vt [B][64][2048] bf16.
// ---------------------------------------------------------------------------
__global__ __launch_bounds__(256) void gemm_proj(
    const void* __restrict__ xq, const void* __restrict__ xk,
    const void* __restrict__ xv,
    const unsigned short* __restrict__ WqT, const unsigned short* __restrict__ WkT,
    const unsigned short* __restrict__ WvT,
    const void* __restrict__ bq, const void* __restrict__ bk,
    const void* __restrict__ bv, const unsigned int* __restrict__ mask,
    unsigned short* __restrict__ oq, unsigned short* __restrict__ ok,
    unsigned short* __restrict__ ovt) {
  __shared__ __align__(16) short sA[64][72];
  __shared__ __align__(16) short sW[64][72];
  const int sel = blockIdx.y;
  const void* x = (sel == 0) ? xq : (sel == 1) ? xk : xv;
  const unsigned short* WT = (sel == 0) ? WqT : (sel == 1) ? WkT : WvT;
  const void* bias = (sel == 0) ? bq : (sel == 1) ? bk : bv;
  const bool isbf = det_bf(mask);

  const int tid = threadIdx.x;
  const int w = tid >> 6, lane = tid & 63;
  const int q_ = lane >> 4, n_ = lane & 15;
  const int row0 = blockIdx.x * 64;

  floatx4 acc[4];
#pragma unroll
  for (int j = 0; j < 4; ++j) acc[j] = (floatx4){0.f, 0.f, 0.f, 0.f};

  for (int k0 = 0; k0 < DM_; k0 += 64) {
    if (isbf) {
#pragma unroll
      for (int it = 0; it < 2; ++it) {
        int idx = tid + it * 256;
        int rr = idx >> 3, cc = (idx & 7) * 8;
        *(uint4*)&sA[rr][cc] =
            *(const uint4*)((const unsigned short*)x + (size_t)(row0 + rr) * DM_ + k0 + cc);
      }
    } else {
#pragma unroll
      for (int it = 0; it < 4; ++it) {
        int idx = tid + it * 256;
        int rr = idx >> 4, cc = (idx & 15) * 4;
        float4 f = *(const float4*)((const float*)x + (size_t)(row0 + rr) * DM_ + k0 + cc);
        unsigned short p[4] = {f2bf(f.x), f2bf(f.y), f2bf(f.z), f2bf(f.w)};
        *(uint2*)&sA[rr][cc] = *(uint2*)p;
      }
    }
#pragma unroll
    for (int it = 0; it < 2; ++it) {
      int idx = tid + it * 256;
      int rr = idx >> 3, cc = (idx & 7) * 8;
      *(uint4*)&sW[rr][cc] = *(const uint4*)(WT + (size_t)rr * DM_ + k0 + cc);
    }
    __syncthreads();
    short8 a0 = *(const short8*)&sA[16 * w + n_][8 * q_];
    short8 a1 = *(const short8*)&sA[16 * w + n_][32 + 8 * q_];
#pragma unroll
    for (int nb = 0; nb < 4; ++nb) {
      short8 b0 = *(const short8*)&sW[16 * nb + n_][8 * q_];
      short8 b1 = *(const short8*)&sW[16 * nb + n_][32 + 8 * q_];
      acc[nb] = MFMA(a0, b0, acc[nb]);
      acc[nb] = MFMA(a1, b1, acc[nb]);
    }
    __syncthreads();
  }

#pragma unroll
  for (int nb = 0; nb < 4; ++nb) {
    const int col = 16 * nb + n_;
    const float bb = ldf(bias, col, isbf);
#pragma unroll
    for (int r = 0; r < 4; ++r) {
      int row = row0 + 16 * w + 4 * q_ + r;
      unsigned short val = f2bf(acc[nb][r] + bb);
      if (sel < 2) {
        unsigned short* o = (sel == 0) ? oq : ok;
        o[(size_t)row * HD_ + col] = val;
      } else {
        int b = row >> 11, s = row & 2047;
        ovt[(((size_t)(b * HD_ + col)) << 11) + s] = val;
      }
    }
  }
}

// ---------------------------------------------------------------------------
// Chunk mapping (R7 table): 80 chunks/hb, grid 1280; hb = id&15,
// rem = 79 - id/16 (LONG chunks get the lowest blockIdx -> dispatched first).
// ti 0..7 -> 1 chunk; 8..15 -> 2; 16..23 -> 3; 24..31 -> 4. Max 8 K-steps.
// Multi-chunk tiles (ti>=8) store partials at slot hb*72 + pbase(ti) + c.
// ---------------------------------------------------------------------------
__device__ __forceinline__ int pbase_of(int ti) {
  return (ti < 16) ? (ti - 8) * 2 : (ti < 24) ? 16 + (ti - 16) * 3
                                              : 40 + (ti - 24) * 4;
}

// ---------------------------------------------------------------------------
// K2: fused causal attention (R17 structure, unchanged). grid 1280, 4
// waves/block, 16-row q-strips. K double-buffered, V + E-panel rings, all
// DMA-staged with pre-swizzled source. ONE barrier + ONE counted vmcnt(2)
// per step. Deferred PV (T15). vmcnt(0) only in the epilogue.
// ---------------------------------------------------------------------------
__global__ __launch_bounds__(256, 2) void attn_kernel(
    const unsigned short* __restrict__ qh, const unsigned short* __restrict__ kh,
    const unsigned short* __restrict__ vt, const unsigned short* __restrict__ E,
    unsigned short* __restrict__ ctxo, float* __restrict__ pc,
    float* __restrict__ ml) {
  __shared__ __align__(16) short sK[2][64][64];    // 16 KB
  __shared__ __align__(16) short sVT[3][64][64];   // 24 KB (ring)
  __shared__ __align__(16) short sE3[3][64][64];   // 24 KB (panel ring)
  __shared__ __align__(16) short sP[64][64];       // 8 KB; wave w rows [16w,16w+16)

  const int id = blockIdx.x;
  const int hb = id & 15;        // all chunks of hb share id%8 -> same XCD
  const int rem = 79 - (id >> 4);  // long chunks first in dispatch order
  int ti, c, nc;
  if (rem < 8)       { ti = rem;                 c = 0;            nc = 1; }
  else if (rem < 24) { ti = 8 + ((rem - 8) >> 1);  c = (rem - 8) & 1;  nc = 2; }
  else if (rem < 48) { ti = 16 + (rem - 24) / 3;   c = (rem - 24) % 3; nc = 3; }
  else               { ti = 24 + ((rem - 48) >> 2); c = (rem - 48) & 3; nc = 4; }
  const int nsteps = ti + 1;
  const int klo = (c * nsteps) / nc;
  const int khi = ((c + 1) * nsteps) / nc;

  const int h = hb >> 1, b = hb & 1;
  const int t0 = ti * 64;

  const int tid = threadIdx.x;
  const int w = tid >> 6, lane = tid & 63;
  const int q_ = lane >> 4, n_ = lane & 15;

  const int trow = t0 + 16 * w + n_;
  const unsigned short* qp = qh + (((size_t)((b << 11) + trow)) << 6) + (q_ << 3);
  const short8 qa0 = *(const short8*)qp;
  const short8 qa1 = *(const short8*)(qp + 32);

  short8 onesf;
#pragma unroll
  for (int j = 0; j < 8; ++j) onesf[j] = (short)0x3F80;  // bf16 1.0

  floatx4 ctxa[4];
#pragma unroll
  for (int nb = 0; nb < 4; ++nb) ctxa[nb] = (floatx4){0.f, 0.f, 0.f, 0.f};
  floatx4 lacc = (floatx4){0.f, 0.f, 0.f, 0.f};

  const unsigned short* eb = E + ((size_t)h << 17);
  const unsigned short* kbase = kh + (((size_t)(b << 11)) << 6);
  const unsigned short* vbase = vt + (((size_t)(b << 6)) << 11);

  // DMA staging geometry. Each gl_lds16 covers 8 rows x 8 chunks (64 lanes x
  // 16B, LDS dest linear). Source col-chunk pre-XOR'd with row&7 so the
  // linear LDS dest ends up XOR-swizzled.
  const int lrow8 = lane >> 3;                     // 0..7
  const int lch = ((lane & 7) ^ lrow8) << 3;       // swizzled source col
  const int rK0 = 8 * w + lrow8;
  // Swizzled read cols (logical chunk q_ / q_+4 of a row with row%8 == n_&7):
  const int c0s = ((q_ ^ (n_ & 7)) << 3);
  const int c1s = (((q_ | 4) ^ (n_ & 7)) << 3);

// Issue-order-pinned staging groups (vmcnt FIFO arithmetic depends on order):
#define STAGE_K(kbuf, s0v)                                                     \
  {                                                                            \
    const unsigned short* gK =                                                 \
        kbase + (((size_t)((s0v) + rK0)) << 6) + lch;                          \
    gl_lds16(gK, (void*)&sK[kbuf][8 * w][0]);                                  \
    gl_lds16(gK + (32 << 6), (void*)(&sK[kbuf][8 * w][0] + 32 * 64));          \
  }
#define STAGE_E(slot, panel)                                                   \
  {                                                                            \
    _Pragma("unroll") for (int j = 0; j < 2; ++j) {                            \
      int gr = 64 * (panel) + 16 * w + 8 * j + lrow8;                          \
      if (gr > T_ - 1) gr = T_ - 1; /* clamped rows are masked s>t */          \
      gl_lds16(eb + ((size_t)gr << 6) + lch,                                   \
               (void*)&sE3[slot][16 * w + 8 * j][0]);                          \
    }                                                                          \
  }
#define STAGE_V(vbuf, s0v)                                                     \
  {                                                                            \
    const unsigned short* gV =                                                 \
        vbase + (((size_t)rK0) << 11) + (s0v) + lch;                           \
    gl_lds16(gV, (void*)&sVT[vbuf][8 * w][0]);                                 \
    gl_lds16(gV + (32 << 11), (void*)(&sVT[vbuf][8 * w][0] + 32 * 64));        \
  }

  // Prologue (issue order K, E, E, V -> 8 outstanding; the loop's counted
  // waits cover the retirement).
  const int p0 = 31 + klo - ti;         // first window panel (>= 0)
  {
    STAGE_K(0, klo * 64);
    __builtin_amdgcn_sched_barrier(0);
    STAGE_E(p0 % 3, p0);
    STAGE_E((p0 + 1) % 3, p0 + 1);
    __builtin_amdgcn_sched_barrier(0);
    STAGE_V(0, klo * 64);
  }

  short8 pa0p = {0, 0, 0, 0, 0, 0, 0, 0};  // deferred-PV fragments,
  short8 pa1p = {0, 0, 0, 0, 0, 0, 0, 0};  // carried across the barrier

  // Wrap counters (avoid mod-3 magic-mul):
  int vcur = 0;                 // V ring slot of this step
  int slotA = p0 % 3;           // E panel slot: window rows 0..63
  int slotB = slotA + 1 == 3 ? 0 : slotA + 1;  // window rows 64..127

  for (int kt = klo; kt < khi; ++kt) {
    const int ph = (kt - klo) & 1;       // K double-buffer phase
    const int s0 = kt * 64;
    const int slotC = slotB + 1 == 3 ? 0 : slotB + 1;  // staging target
    const int vnext = vcur + 1 == 3 ? 0 : vcur + 1;
    const int vprev = vcur == 0 ? 2 : vcur - 1;

    // ---- step top: retire {V(s-1), K(s), E(s)}; V(s) stays in flight ----
    asm volatile("s_waitcnt vmcnt(2)" ::: "memory");
    __builtin_amdgcn_sched_barrier(0);
    __builtin_amdgcn_s_barrier();
    __builtin_amdgcn_sched_barrier(0);

    // Issue next step's staging (K -> E -> V, order pinned).
    if (kt + 1 < khi) {
      STAGE_K(ph ^ 1, s0 + 64);
      __builtin_amdgcn_sched_barrier(0);
      STAGE_E(slotC, p0 + (kt - klo) + 2);
      __builtin_amdgcn_sched_barrier(0);
      STAGE_V(vnext, s0 + 64);
    }

    // ---- QK MFMA from LDS K ----
    floatx4 qk[4];
    __builtin_amdgcn_s_setprio(1);
#pragma unroll
    for (int nb = 0; nb < 4; ++nb) {
      short8 kb0 = *(const short8*)&sK[ph][16 * nb + n_][c0s];
      short8 kb1 = *(const short8*)&sK[ph][16 * nb + n_][c1s];
      qk[nb] = (floatx4){0.f, 0.f, 0.f, 0.f};
      qk[nb] = MFMA(qa0, kb0, qk[nb]);
      qk[nb] = MFMA(qa1, kb1, qk[nb]);
    }
    // ---- QE MFMA from E panel ring ----
    floatx4 qe[5];
#pragma unroll
    for (int f = 0; f < 5; ++f) {
      const int row16 = 16 * (3 - w + f);          // 0..112, 16-aligned
      const short* ep = (row16 < 64) ? &sE3[slotA][row16 + n_][0]
                                     : &sE3[slotB][row16 - 64 + n_][0];
      short8 eb0 = *(const short8*)(ep + c0s);
      short8 eb1 = *(const short8*)(ep + c1s);
      qe[f] = (floatx4){0.f, 0.f, 0.f, 0.f};
      qe[f] = MFMA(qa0, eb0, qe[f]);
      qe[f] = MFMA(qa1, eb1, qe[f]);
    }
    // ---- deferred PV + l for step kt-1 (V(s-1) retired at step top;
    //      independent of QK/QE/skew -> fills their latency shadow) ----
    if (kt > klo) {
#pragma unroll
      for (int nb = 0; nb < 4; ++nb) {
        short8 v0 = *(const short8*)&sVT[vprev][16 * nb + n_][c0s];
        short8 v1 = *(const short8*)&sVT[vprev][16 * nb + n_][c1s];
        ctxa[nb] = MFMA(pa0p, v0, ctxa[nb]);
        ctxa[nb] = MFMA(pa1p, v1, ctxa[nb]);
      }
      lacc = MFMA(pa0p, onesf, lacc);
      lacc = MFMA(pa1p, onesf, lacc);
    }
    __builtin_amdgcn_s_setprio(0);

    // ---- skew diagonal (16 bpermute, source-side frag select) + exp + sP --
    const bool diag = (kt == ti);
#pragma unroll
    for (int r = 0; r < 4; ++r) {
      const int t = 4 * q_ + r;
      const int ba = ((q_ << 4) | ((n_ - t + 15) & 15)) << 2;
      const int nd = (n_ + t + 1) & 15;   // dest lane (same q_) pulling from us
      const bool hi = nd > t;             // dest picks qe[mb+1] iff its n_ > t
      const int swr = (t & 7) << 3;       // sP row-swizzle term
#pragma unroll
      for (int mb = 0; mb < 4; ++mb) {
        float merged = hi ? qe[mb + 1][r] : qe[mb][r];
        float g = __int_as_float(
            __builtin_amdgcn_ds_bpermute(ba, __float_as_int(merged)));
        float sv = qk[mb][r] + g;
        if (diag && (16 * mb + n_ > 16 * w + t)) sv = -1.0e30f;  // exp -> 0
        // exp(sv*0.125) == exp2(sv * 0.125*log2(e))
        sP[16 * w + t][(16 * mb + n_) ^ swr] =
            (short)f2bf(exp2f(sv * 0.18033688011f));
      }
    }

    // ---- read own P strip into regs for NEXT step's deferred PV ----
    pa0p = *(const short8*)&sP[16 * w + n_][c0s];
    pa1p = *(const short8*)&sP[16 * w + n_][c1s];

    // Advance ring counters.
    vcur = vnext;
    slotA = slotB;
    slotB = slotC;
  }
#undef STAGE_K
#undef STAGE_E
#undef STAGE_V

  // ---- epilogue: V(khi-1) fully retired, then last PV + l ----
  asm volatile("s_waitcnt vmcnt(0)" ::: "memory");
  __builtin_amdgcn_sched_barrier(0);
  __builtin_amdgcn_s_barrier();
  __builtin_amdgcn_sched_barrier(0);
  {
    const int vlast = vcur == 0 ? 2 : vcur - 1;  // slot of step khi-1
    __builtin_amdgcn_s_setprio(1);
#pragma unroll
    for (int nb = 0; nb < 4; ++nb) {
      short8 v0 = *(const short8*)&sVT[vlast][16 * nb + n_][c0s];
      short8 v1 = *(const short8*)&sVT[vlast][16 * nb + n_][c1s];
      ctxa[nb] = MFMA(pa0p, v0, ctxa[nb]);
      ctxa[nb] = MFMA(pa1p, v1, ctxa[nb]);
    }
    lacc = MFMA(pa0p, onesf, lacc);
    lacc = MFMA(pa1p, onesf, lacc);
    __builtin_amdgcn_s_setprio(0);
  }

  if (nc == 1) {
#pragma unroll
    for (int r = 0; r < 4; ++r) {
      const float inv = 1.0f / lacc[r];
      const int row = t0 + 16 * w + 4 * q_ + r;
      const size_t base = (((size_t)((b << 11) + row)) << 9) + (h << 6) + n_;
#pragma unroll
      for (int nb = 0; nb < 4; ++nb)
        ctxo[base + 16 * nb] = f2bf(ctxa[nb][r] * inv);
    }
  } else {
    const int idx = hb * 72 + pbase_of(ti) + c;
    float* pcb = pc + ((size_t)idx << 12);   // *4096
    float* mlb = ml + ((size_t)idx << 6);    // *64
#pragma unroll
    for (int r = 0; r < 4; ++r) {
      const int row = 16 * w + 4 * q_ + r;
#pragma unroll
      for (int nb = 0; nb < 4; ++nb)
        pcb[(row << 6) + 16 * nb + n_] = ctxa[nb][r];
      if (n_ == 0) mlb[row] = lacc[r];
    }
  }
}

// ---------------------------------------------------------------------------
// K2b: combine chunk partials: out = sum(c_i) / sum(l_i). grid 384 blocks
// (16 hb x 24 multi-chunk tiles, ti 8..31).
// ---------------------------------------------------------------------------
__global__ __launch_bounds__(256) void combine_kernel(
    const float* __restrict__ pc, const float* __restrict__ ml,
    unsigned short* __restrict__ ctxo) {
  const int cb = blockIdx.x;
  const int hb = cb / 24;
  const int ti = 8 + cb % 24;
  const int nc = (ti >> 3) + 1;
  const int h = hb >> 1, b = hb & 1, t0 = ti * 64;
  const int tid = threadIdx.x;
  const int row = tid >> 2, seg = (tid & 3) * 16;
  const int idx0 = hb * 72 + pbase_of(ti);

  float lsum = 0.f;
  float4 a4[4];
#pragma unroll
  for (int j = 0; j < 4; ++j) a4[j] = (float4){0.f, 0.f, 0.f, 0.f};
  for (int c = 0; c < nc; ++c) {
    const int idx = idx0 + c;
    lsum += ml[((size_t)idx << 6) + row];
    const float* cp = pc + ((size_t)idx << 12) + (row << 6) + seg;
#pragma unroll
    for (int j = 0; j < 4; ++j) {
      float4 x = *(const float4*)(cp + 4 * j);
      a4[j].x += x.x; a4[j].y += x.y; a4[j].z += x.z; a4[j].w += x.w;
    }
  }
  const float inv = 1.0f / lsum;
  unsigned short o[16];
#pragma unroll
  for (int j = 0; j < 4; ++j) {
    o[4 * j + 0] = f2bf(a4[j].x * inv);
    o[4 * j + 1] = f2bf(a4[j].y * inv);
    o[4 * j + 2] = f2bf(a4[j].z * inv);
    o[4 * j + 3] = f2bf(a4[j].w * inv);
  }
  unsigned short* dst =
      ctxo + (((size_t)((b << 11) + t0 + row)) << 9) + (h << 6) + seg;
  *(uint4*)dst = *(uint4*)&o[0];
  *(uint4*)(dst + 8) = *(uint4*)&o[8];
}

// ---------------------------------------------------------------------------
// K3 (R18): MFMA GEMM with DMA staging. A bf16 [4096][512] @ WT bf16
// [Npad][512] + bias, tile 64x64, K-steps of 64, double-buffered swizzled
// LDS filled by global_load_lds (pre-swizzled source), ONE s_barrier +
// vmcnt(0) per step. RELU=1: out h1 bf16 [4096][512]. RELU=0: out d_out
// (dtype per mask), N=388 (WlT has 448 rows; max row read = 447).
// ---------------------------------------------------------------------------
template <int RELU>
__global__ __launch_bounds__(256) void mlp_mfma(
    const unsigned short* __restrict__ A, const unsigned short* __restrict__ WT,
    const void* __restrict__ bias, unsigned short* __restrict__ outBF,
    void* __restrict__ outD, const unsigned int* __restrict__ mask) {
  __shared__ __align__(16) short sA[2][64][64];   // 16 KB
  __shared__ __align__(16) short sW[2][64][64];   // 16 KB
  const int tid = threadIdx.x;
  const int w = tid >> 6, lane = tid & 63;
  const int q_ = lane >> 4, n_ = lane & 15;
  const int row0 = blockIdx.x * 64;
  const int n0 = blockIdx.y * 64;
  const bool isbf = det_bf(mask);

  const int lrow8 = lane >> 3;                     // 0..7
  const int lch = ((lane & 7) ^ lrow8) << 3;       // swizzled source col
  const int c0s = ((q_ ^ (n_ & 7)) << 3);
  const int c1s = (((q_ | 4) ^ (n_ & 7)) << 3);

#define MSTAGE(buf, k0v)                                                       \
  {                                                                            \
    const unsigned short* gA =                                                 \
        A + (size_t)(row0 + 16 * w + lrow8) * DM_ + (k0v) + lch;               \
    const unsigned short* gW =                                                 \
        WT + (size_t)(n0 + 16 * w + lrow8) * DM_ + (k0v) + lch;                \
    gl_lds16(gA, (void*)&sA[buf][16 * w][0]);                                  \
    gl_lds16(gA + 8 * DM_, (void*)(&sA[buf][16 * w][0] + 8 * 64));             \
    gl_lds16(gW, (void*)&sW[buf][16 * w][0]);                                  \
    gl_lds16(gW + 8 * DM_, (void*)(&sW[buf][16 * w][0] + 8 * 64));             \
  }

  floatx4 acc[4];
#pragma unroll
  for (int j = 0; j < 4; ++j) acc[j] = (floatx4){0.f, 0.f, 0.f, 0.f};

  MSTAGE(0, 0);
  for (int ks = 0; ks < DM_ / 64; ++ks) {
    const int buf = ks & 1;
    asm volatile("s_waitcnt vmcnt(0)" ::: "memory");
    __builtin_amdgcn_sched_barrier(0);
    __builtin_amdgcn_s_barrier();
    __builtin_amdgcn_sched_barrier(0);
    if (ks + 1 < DM_ / 64) MSTAGE(buf ^ 1, (ks + 1) * 64);

    short8 a0 = *(const short8*)&sA[buf][16 * w + n_][c0s];
    short8 a1 = *(const short8*)&sA[buf][16 * w + n_][c1s];
    __builtin_amdgcn_s_setprio(1);
#pragma unroll
    for (int nb = 0; nb < 4; ++nb) {
      short8 b0 = *(const short8*)&sW[buf][16 * nb + n_][c0s];
      short8 b1 = *(const short8*)&sW[buf][16 * nb + n_][c1s];
      acc[nb] = MFMA(a0, b0, acc[nb]);
      acc[nb] = MFMA(a1, b1, acc[nb]);
    }
    __builtin_amdgcn_s_setprio(0);
  }
#undef MSTAGE

#pragma unroll
  for (int nb = 0; nb < 4; ++nb) {
    const int col = n0 + 16 * nb + n_;
    float bb = 0.f;
    if (RELU || col < EV_) bb = ldf(bias, col, isbf);
#pragma unroll
    for (int r = 0; r < 4; ++r) {
      const int row = row0 + 16 * w + 4 * q_ + r;
      float v = acc[nb][r] + bb;
      if (RELU) {
        outBF[(size_t)row * ED_ + col] = f2bf(fmaxf(v, 0.f));
      } else if (col < EV_) {
        if (isbf) ((unsigned short*)outD)[(size_t)row * EV_ + col] = f2bf(v);
        else      ((float*)outD)[(size_t)row * EV_ + col] = v;
      }
    }
  }
}

// ---------------------------------------------------------------------------
extern "C" void kernel_launch(void* const* d_in, const int* in_sizes, int n_in,
                              void* d_out, int out_size, void* d_ws, size_t ws_size,
                              hipStream_t stream) {
  const void* v  = d_in[0];
  const void* k  = d_in[1];
  const void* q  = d_in[2];
  const unsigned int* mask = (const unsigned int*)d_in[3];
  const void* Wq = d_in[4];
  const void* bq = d_in[5];
  const void* Wk = d_in[6];
  const void* bk = d_in[7];
  const void* Wv = d_in[8];
  const void* bv = d_in[9];
  const void* E  = d_in[10];
  const void* Wo = d_in[11];
  const void* bo = d_in[12];
  const void* Wl = d_in[13];
  const void* bl = d_in[14];

  char* p = (char*)d_ws;
  unsigned short* E_c  = (unsigned short*)p; p += (size_t)H_ * T_ * HD_ * 2;  // 2 MB
  unsigned short* qhb  = (unsigned short*)p; p += (size_t)BT_ * HD_ * 2;
  unsigned short* khb  = (unsigned short*)p; p += (size_t)BT_ * HD_ * 2;
  unsigned short* vtb  = (unsigned short*)p; p += (size_t)BT_ * HD_ * 2;
  unsigned short* WqT  = (unsigned short*)p; p += (size_t)HD_ * DM_ * 2;
  unsigned short* WkT  = (unsigned short*)p; p += (size_t)HD_ * DM_ * 2;
  unsigned short* WvT  = (unsigned short*)p; p += (size_t)HD_ * DM_ * 2;
  unsigned short* WoT  = (unsigned short*)p; p += (size_t)ED_ * DM_ * 2;
  unsigned short* WlT  = (unsigned short*)p; p += (size_t)448 * DM_ * 2;
  unsigned short* ctxb = (unsigned short*)p; p += (size_t)BT_ * DM_ * 2;      // 4 MB
  unsigned short* h1b  = (unsigned short*)p; p += (size_t)BT_ * ED_ * 2;      // 4 MB
  float* pc = (float*)p; p += (size_t)16 * 72 * 4096 * 4;                     // 18.9 MB
  float* ml = (float*)p; p += (size_t)16 * 72 * 64 * 4;                       // 0.3 MB

  prep_kernel<<<dim3(1312), 256, 0, stream>>>(
      E, Wq, Wk, Wv, Wo, Wl, mask, E_c, WqT, WkT, WvT, WoT, WlT);
  gemm_proj<<<dim3(BT_ / 64, 3), 256, 0, stream>>>(
      q, k, v, WqT, WkT, WvT, bq, bk, bv, mask, qhb, khb, vtb);
  attn_kernel<<<dim3(1280), 256, 0, stream>>>(qhb, khb, vtb, E_c, ctxb, pc, ml);
  combine_kernel<<<dim3(384), 256, 0, stream>>>(pc, ml, ctxb);
  mlp_mfma<1><<<dim3(BT_ / 64, ED_ / 64), 256, 0, stream>>>(
      ctxb, WoT, bo, h1b, nullptr, mask);
  mlp_mfma<0><<<dim3(BT_ / 64, 448 / 64), 256, 0, stream>>>(
      h1b, WlT, bl, nullptr, d_out, mask);
}

// Round 12
// 190.160 us; speedup vs baseline: 1.2407x; 1.0400x over previous
//
#include <hip/hip_runtime.h>
#include <hip/hip_bf16.h>

// Music-Transformer RelativeGlobalAttention, MI355X round 19.
// B=2, T=2048, D=512, H=8, hd=64, ED=512, EV=388. fp32 I/O (runtime-detected
// via mask[0] bit pattern), bf16 MFMA compute, fp32 accumulation.
// R19: attn kept at R17 (53us), mlp at R18. gemm_proj rewritten with the
// DMA pipeline: A staged by global_load_lds AS RAW FP32 (16B chunks, 4-bit
// XOR chunk swizzle; f32->bf16 conversion moved to fragment-read time, 16
// cvt/wave-step) or as bf16 directly when input is bf16; W staged by DMA
// from WqT (mlp pattern); double-buffer; ONE s_barrier + vmcnt(0) per
// K-step (was 2 syncthreads + vector staging). LDS 48KB. This round is also
// the fixed-overhead probe: if total moves <1.5us, remainder is harness
// overhead and the pipeline is at its plateau.

#define B_ 2
#define T_ 2048
#define DM_ 512
#define H_ 8
#define HD_ 64
#define ED_ 512
#define EV_ 388
#define BT_ (B_ * T_)

typedef __attribute__((ext_vector_type(8))) short short8;
typedef __attribute__((ext_vector_type(4))) float floatx4;

#define MFMA(a, b, c) __builtin_amdgcn_mfma_f32_16x16x32_bf16((a), (b), (c), 0, 0, 0)

__device__ __forceinline__ float bfs(unsigned short s) {
  union { unsigned int i; float f; } v; v.i = ((unsigned int)s) << 16; return v.f;
}
__device__ __forceinline__ unsigned short f2bf(float f) {
  __hip_bfloat16 h = __float2bfloat16(f);
  union { __hip_bfloat16 h; unsigned short u; } v; v.h = h; return v.u;
}
__device__ __forceinline__ float ldf(const void* p, int i, bool isbf) {
  return isbf ? bfs(((const unsigned short*)p)[i]) : ((const float*)p)[i];
}
__device__ __forceinline__ bool det_bf(const unsigned int* mask) {
  return mask[0] != 0x3F800000u;  // fp32 1.0f word; bf16-packed differs
}
__device__ __forceinline__ void gl_lds16(const void* g, void* l) {
  __builtin_amdgcn_global_load_lds(
      (const __attribute__((address_space(1))) void*)g,
      (__attribute__((address_space(3))) void*)l, 16, 0, 0);
}

// ---------------------------------------------------------------------------
// K0 prep: [0,1024) E->bf16 copy/convert; [1024,1312) weight transposes
// src [512][N] -> dst [Npad][512] bf16, zero-padded rows.
// ---------------------------------------------------------------------------
__global__ __launch_bounds__(256) void prep_kernel(
    const void* __restrict__ E, const void* __restrict__ Wq,
    const void* __restrict__ Wk, const void* __restrict__ Wv,
    const void* __restrict__ Wo, const void* __restrict__ Wl,
    const unsigned int* __restrict__ mask,
    unsigned short* __restrict__ E_c, unsigned short* __restrict__ WqT,
    unsigned short* __restrict__ WkT, unsigned short* __restrict__ WvT,
    unsigned short* __restrict__ WoT, unsigned short* __restrict__ WlT) {
  const bool isbf = det_bf(mask);
  const int tid = threadIdx.x;
  int bi = blockIdx.x;
  if (bi < 1024) {
    const int i0 = (bi * 256 + tid) * 4;
    if (isbf) {
      *(uint2*)&E_c[i0] = *(const uint2*)((const unsigned short*)E + i0);
    } else {
      float4 f = *(const float4*)((const float*)E + i0);
      unsigned short p[4] = {f2bf(f.x), f2bf(f.y), f2bf(f.z), f2bf(f.w)};
      *(uint2*)&E_c[i0] = *(uint2*)p;
    }
    return;
  }
  bi -= 1024;
  const void* src; unsigned short* dst; int N, nb;
  if (bi < 16)       { src = Wq; dst = WqT; N = 64;  nb = bi; }
  else if (bi < 32)  { src = Wk; dst = WkT; N = 64;  nb = bi - 16; }
  else if (bi < 48)  { src = Wv; dst = WvT; N = 64;  nb = bi - 32; }
  else if (bi < 176) { src = Wo; dst = WoT; N = 512; nb = bi - 48; }
  else               { src = Wl; dst = WlT; N = 388; nb = bi - 176; }
  const int n = nb * 4 + (tid >> 6);
  const int k0 = (tid & 63) * 8;
  unsigned short vv[8];
#pragma unroll
  for (int j = 0; j < 8; ++j) {
    if (n >= N) vv[j] = 0;
    else if (isbf) vv[j] = ((const unsigned short*)src)[(size_t)(k0 + j) * N + n];
    else vv[j] = f2bf(((const float*)src)[(size_t)(k0 + j) * N + n]);
  }
  *(uint4*)&dst[(size_t)n * DM_ + k0] = *(uint4*)vv;
}

// ---------------------------------------------------------------------------
// K1 (R19): projections with DMA pipeline. grid (64, 3), tile 64x64, block
// 256 (4 waves). A staged as raw fp32 via global_load_lds (4-bit XOR chunk
// swizzle, convert at frag-read) or bf16 directly; W staged by DMA from WT.
// Double-buffered, ONE s_barrier + vmcnt(0) per K-step.
// sel 0/1 -> qh/kh row-major bf16 [4096][64]; sel 2 -> vt [B][64][2048] bf16.
// ---------------------------------------------------------------------------
__global__ __launch_bounds__(256) void gemm_proj(
    const void* __restrict__ xq, const void* __restrict__ xk,
    const void* __restrict__ xv,
    const unsigned short* __restrict__ WqT, const unsigned short* __restrict__ WkT,
    const unsigned short* __restrict__ WvT,
    const void* __restrict__ bq, const void* __restrict__ bk,
    const void* __restrict__ bv, const unsigned int* __restrict__ mask,
    unsigned short* __restrict__ oq, unsigned short* __restrict__ ok,
    unsigned short* __restrict__ ovt) {
  __shared__ __align__(16) float sAf[2][64][64];   // 32 KB (fp32-A path)
  __shared__ __align__(16) short sW[2][64][64];    // 16 KB
  short(*sAb)[64][64] = (short(*)[64][64])sAf;     // bf16-A alias (16 KB)

  const int sel = blockIdx.y;
  const void* x = (sel == 0) ? xq : (sel == 1) ? xk : xv;
  const unsigned short* WT = (sel == 0) ? WqT : (sel == 1) ? WkT : WvT;
  const void* bias = (sel == 0) ? bq : (sel == 1) ? bk : bv;
  const bool isbf = det_bf(mask);

  const int tid = threadIdx.x;
  const int w = tid >> 6, lane = tid & 63;
  const int q_ = lane >> 4, n_ = lane & 15;
  const int row0 = blockIdx.x * 64;

  // W/bf16-A staging geometry (8 chunks of 16B per 128B row, row&7 XOR):
  const int lrow8 = lane >> 3;                   // 0..7
  const int lchW = ((lane & 7) ^ lrow8) << 3;    // swizzled source col (shorts)
  const int c0s = ((q_ ^ (n_ & 7)) << 3);        // bf16 read col lo
  const int c1s = (((q_ | 4) ^ (n_ & 7)) << 3);  // bf16 read col hi
  // fp32-A staging geometry (16 chunks of 16B per 256B row, row&15 XOR):
  const int arow4 = lane >> 4;                   // 0..3
  const int achk = lane & 15;                    // phys chunk

#define PSTAGE_W(buf, k0v)                                                     \
  {                                                                            \
    const unsigned short* gW =                                                 \
        WT + (size_t)(16 * w + lrow8) * DM_ + (k0v) + lchW;                    \
    gl_lds16(gW, (void*)&sW[buf][16 * w][0]);                                  \
    gl_lds16(gW + 8 * DM_, (void*)(&sW[buf][16 * w][0] + 8 * 64));             \
  }
#define PSTAGE_AB(buf, k0v)                                                    \
  {                                                                            \
    const unsigned short* gA = (const unsigned short*)x +                      \
        (size_t)(row0 + 16 * w + lrow8) * DM_ + (k0v) + lchW;                  \
    gl_lds16(gA, (void*)&sAb[buf][16 * w][0]);                                 \
    gl_lds16(gA + 8 * DM_, (void*)(&sAb[buf][16 * w][0] + 8 * 64));            \
  }
#define PSTAGE_AF(buf, k0v)                                                    \
  {                                                                            \
    _Pragma("unroll") for (int j = 0; j < 4; ++j) {                            \
      const int r = 16 * w + 4 * j + arow4;                                    \
      const int lc = (achk ^ (r & 15)) << 2; /* float offset in row */         \
      gl_lds16((const void*)((const float*)x +                                 \
                             (size_t)(row0 + r) * DM_ + (k0v) + lc),           \
               (void*)&sAf[buf][16 * w + 4 * j][0]);                           \
    }                                                                          \
  }
#define PSTAGE_A(buf, k0v)                                                     \
  { if (isbf) PSTAGE_AB(buf, k0v) else PSTAGE_AF(buf, k0v) }

  floatx4 acc[4];
#pragma unroll
  for (int j = 0; j < 4; ++j) acc[j] = (floatx4){0.f, 0.f, 0.f, 0.f};

  PSTAGE_A(0, 0);
  PSTAGE_W(0, 0);
  for (int ks = 0; ks < DM_ / 64; ++ks) {
    const int buf = ks & 1;
    asm volatile("s_waitcnt vmcnt(0)" ::: "memory");
    __builtin_amdgcn_sched_barrier(0);
    __builtin_amdgcn_s_barrier();
    __builtin_amdgcn_sched_barrier(0);
    if (ks + 1 < DM_ / 64) {
      PSTAGE_A(buf ^ 1, (ks + 1) * 64);
      PSTAGE_W(buf ^ 1, (ks + 1) * 64);
    }

    short8 a0, a1;
    if (isbf) {
      a0 = *(const short8*)&sAb[buf][16 * w + n_][c0s];
      a1 = *(const short8*)&sAb[buf][16 * w + n_][c1s];
    } else {
      // row 16w+n_ (row&15 == n_); logical chunks 2q_,2q_+1 / 2q_+8,2q_+9.
      const float* ar = &sAf[buf][16 * w + n_][0];
      floatx4 f0 = *(const floatx4*)(ar + (((2 * q_) ^ n_) << 2));
      floatx4 f1 = *(const floatx4*)(ar + (((2 * q_ + 1) ^ n_) << 2));
      floatx4 f2 = *(const floatx4*)(ar + (((2 * q_ + 8) ^ n_) << 2));
      floatx4 f3 = *(const floatx4*)(ar + (((2 * q_ + 9) ^ n_) << 2));
#pragma unroll
      for (int j = 0; j < 4; ++j) {
        a0[j] = (short)f2bf(f0[j]);
        a0[4 + j] = (short)f2bf(f1[j]);
        a1[j] = (short)f2bf(f2[j]);
        a1[4 + j] = (short)f2bf(f3[j]);
      }
    }
    __builtin_amdgcn_s_setprio(1);
#pragma unroll
    for (int nb = 0; nb < 4; ++nb) {
      short8 b0 = *(const short8*)&sW[buf][16 * nb + n_][c0s];
      short8 b1 = *(const short8*)&sW[buf][16 * nb + n_][c1s];
      acc[nb] = MFMA(a0, b0, acc[nb]);
      acc[nb] = MFMA(a1, b1, acc[nb]);
    }
    __builtin_amdgcn_s_setprio(0);
  }
#undef PSTAGE_W
#undef PSTAGE_AB
#undef PSTAGE_AF
#undef PSTAGE_A

#pragma unroll
  for (int nb = 0; nb < 4; ++nb) {
    const int col = 16 * nb + n_;
    const float bb = ldf(bias, col, isbf);
#pragma unroll
    for (int r = 0; r < 4; ++r) {
      int row = row0 + 16 * w + 4 * q_ + r;
      unsigned short val = f2bf(acc[nb][r] + bb);
      if (sel < 2) {
        unsigned short* o = (sel == 0) ? oq : ok;
        o[(size_t)row * HD_ + col] = val;
      } else {
        int b = row >> 11, s = row & 2047;
        ovt[(((size_t)(b * HD_ + col)) << 11) + s] = val;
      }
    }
  }
}

// ---------------------------------------------------------------------------
// Chunk mapping (R7 table): 80 chunks/hb, grid 1280; hb = id&15,
// rem = 79 - id/16 (LONG chunks get the lowest blockIdx -> dispatched first).
// ti 0..7 -> 1 chunk; 8..15 -> 2; 16..23 -> 3; 24..31 -> 4. Max 8 K-steps.
// Multi-chunk tiles (ti>=8) store partials at slot hb*72 + pbase(ti) + c.
// ---------------------------------------------------------------------------
__device__ __forceinline__ int pbase_of(int ti) {
  return (ti < 16) ? (ti - 8) * 2 : (ti < 24) ? 16 + (ti - 16) * 3
                                              : 40 + (ti - 24) * 4;
}

// ---------------------------------------------------------------------------
// K2: fused causal attention (R17 structure, unchanged). grid 1280, 4
// waves/block, 16-row q-strips. K double-buffered, V + E-panel rings, all
// DMA-staged with pre-swizzled source. ONE barrier + ONE counted vmcnt(2)
// per step. Deferred PV (T15). vmcnt(0) only in the epilogue.
// ---------------------------------------------------------------------------
__global__ __launch_bounds__(256, 2) void attn_kernel(
    const unsigned short* __restrict__ qh, const unsigned short* __restrict__ kh,
    const unsigned short* __restrict__ vt, const unsigned short* __restrict__ E,
    unsigned short* __restrict__ ctxo, float* __restrict__ pc,
    float* __restrict__ ml) {
  __shared__ __align__(16) short sK[2][64][64];    // 16 KB
  __shared__ __align__(16) short sVT[3][64][64];   // 24 KB (ring)
  __shared__ __align__(16) short sE3[3][64][64];   // 24 KB (panel ring)
  __shared__ __align__(16) short sP[64][64];       // 8 KB; wave w rows [16w,16w+16)

  const int id = blockIdx.x;
  const int hb = id & 15;        // all chunks of hb share id%8 -> same XCD
  const int rem = 79 - (id >> 4);  // long chunks first in dispatch order
  int ti, c, nc;
  if (rem < 8)       { ti = rem;                 c = 0;            nc = 1; }
  else if (rem < 24) { ti = 8 + ((rem - 8) >> 1);  c = (rem - 8) & 1;  nc = 2; }
  else if (rem < 48) { ti = 16 + (rem - 24) / 3;   c = (rem - 24) % 3; nc = 3; }
  else               { ti = 24 + ((rem - 48) >> 2); c = (rem - 48) & 3; nc = 4; }
  const int nsteps = ti + 1;
  const int klo = (c * nsteps) / nc;
  const int khi = ((c + 1) * nsteps) / nc;

  const int h = hb >> 1, b = hb & 1;
  const int t0 = ti * 64;

  const int tid = threadIdx.x;
  const int w = tid >> 6, lane = tid & 63;
  const int q_ = lane >> 4, n_ = lane & 15;

  const int trow = t0 + 16 * w + n_;
  const unsigned short* qp = qh + (((size_t)((b << 11) + trow)) << 6) + (q_ << 3);
  const short8 qa0 = *(const short8*)qp;
  const short8 qa1 = *(const short8*)(qp + 32);

  short8 onesf;
#pragma unroll
  for (int j = 0; j < 8; ++j) onesf[j] = (short)0x3F80;  // bf16 1.0

  floatx4 ctxa[4];
#pragma unroll
  for (int nb = 0; nb < 4; ++nb) ctxa[nb] = (floatx4){0.f, 0.f, 0.f, 0.f};
  floatx4 lacc = (floatx4){0.f, 0.f, 0.f, 0.f};

  const unsigned short* eb = E + ((size_t)h << 17);
  const unsigned short* kbase = kh + (((size_t)(b << 11)) << 6);
  const unsigned short* vbase = vt + (((size_t)(b << 6)) << 11);

  // DMA staging geometry. Each gl_lds16 covers 8 rows x 8 chunks (64 lanes x
  // 16B, LDS dest linear). Source col-chunk pre-XOR'd with row&7 so the
  // linear LDS dest ends up XOR-swizzled.
  const int lrow8 = lane >> 3;                     // 0..7
  const int lch = ((lane & 7) ^ lrow8) << 3;       // swizzled source col
  const int rK0 = 8 * w + lrow8;
  // Swizzled read cols (logical chunk q_ / q_+4 of a row with row%8 == n_&7):
  const int c0s = ((q_ ^ (n_ & 7)) << 3);
  const int c1s = (((q_ | 4) ^ (n_ & 7)) << 3);

// Issue-order-pinned staging groups (vmcnt FIFO arithmetic depends on order):
#define STAGE_K(kbuf, s0v)                                                     \
  {                                                                            \
    const unsigned short* gK =                                                 \
        kbase + (((size_t)((s0v) + rK0)) << 6) + lch;                          \
    gl_lds16(gK, (void*)&sK[kbuf][8 * w][0]);                                  \
    gl_lds16(gK + (32 << 6), (void*)(&sK[kbuf][8 * w][0] + 32 * 64));          \
  }
#define STAGE_E(slot, panel)                                                   \
  {                                                                            \
    _Pragma("unroll") for (int j = 0; j < 2; ++j) {                            \
      int gr = 64 * (panel) + 16 * w + 8 * j + lrow8;                          \
      if (gr > T_ - 1) gr = T_ - 1; /* clamped rows are masked s>t */          \
      gl_lds16(eb + ((size_t)gr << 6) + lch,                                   \
               (void*)&sE3[slot][16 * w + 8 * j][0]);                          \
    }                                                                          \
  }
#define STAGE_V(vbuf, s0v)                                                     \
  {                                                                            \
    const unsigned short* gV =                                                 \
        vbase + (((size_t)rK0) << 11) + (s0v) + lch;                           \
    gl_lds16(gV, (void*)&sVT[vbuf][8 * w][0]);                                 \
    gl_lds16(gV + (32 << 11), (void*)(&sVT[vbuf][8 * w][0] + 32 * 64));        \
  }

  // Prologue (issue order K, E, E, V -> 8 outstanding; the loop's counted
  // waits cover the retirement).
  const int p0 = 31 + klo - ti;         // first window panel (>= 0)
  {
    STAGE_K(0, klo * 64);
    __builtin_amdgcn_sched_barrier(0);
    STAGE_E(p0 % 3, p0);
    STAGE_E((p0 + 1) % 3, p0 + 1);
    __builtin_amdgcn_sched_barrier(0);
    STAGE_V(0, klo * 64);
  }

  short8 pa0p = {0, 0, 0, 0, 0, 0, 0, 0};  // deferred-PV fragments,
  short8 pa1p = {0, 0, 0, 0, 0, 0, 0, 0};  // carried across the barrier

  // Wrap counters (avoid mod-3 magic-mul):
  int vcur = 0;                 // V ring slot of this step
  int slotA = p0 % 3;           // E panel slot: window rows 0..63
  int slotB = slotA + 1 == 3 ? 0 : slotA + 1;  // window rows 64..127

  for (int kt = klo; kt < khi; ++kt) {
    const int ph = (kt - klo) & 1;       // K double-buffer phase
    const int s0 = kt * 64;
    const int slotC = slotB + 1 == 3 ? 0 : slotB + 1;  // staging target
    const int vnext = vcur + 1 == 3 ? 0 : vcur + 1;
    const int vprev = vcur == 0 ? 2 : vcur - 1;

    // ---- step top: retire {V(s-1), K(s), E(s)}; V(s) stays in flight ----
    asm volatile("s_waitcnt vmcnt(2)" ::: "memory");
    __builtin_amdgcn_sched_barrier(0);
    __builtin_amdgcn_s_barrier();
    __builtin_amdgcn_sched_barrier(0);

    // Issue next step's staging (K -> E -> V, order pinned).
    if (kt + 1 < khi) {
      STAGE_K(ph ^ 1, s0 + 64);
      __builtin_amdgcn_sched_barrier(0);
      STAGE_E(slotC, p0 + (kt - klo) + 2);
      __builtin_amdgcn_sched_barrier(0);
      STAGE_V(vnext, s0 + 64);
    }

    // ---- QK MFMA from LDS K ----
    floatx4 qk[4];
    __builtin_amdgcn_s_setprio(1);
#pragma unroll
    for (int nb = 0; nb < 4; ++nb) {
      short8 kb0 = *(const short8*)&sK[ph][16 * nb + n_][c0s];
      short8 kb1 = *(const short8*)&sK[ph][16 * nb + n_][c1s];
      qk[nb] = (floatx4){0.f, 0.f, 0.f, 0.f};
      qk[nb] = MFMA(qa0, kb0, qk[nb]);
      qk[nb] = MFMA(qa1, kb1, qk[nb]);
    }
    // ---- QE MFMA from E panel ring ----
    floatx4 qe[5];
#pragma unroll
    for (int f = 0; f < 5; ++f) {
      const int row16 = 16 * (3 - w + f);          // 0..112, 16-aligned
      const short* ep = (row16 < 64) ? &sE3[slotA][row16 + n_][0]
                                     : &sE3[slotB][row16 - 64 + n_][0];
      short8 eb0 = *(const short8*)(ep + c0s);
      short8 eb1 = *(const short8*)(ep + c1s);
      qe[f] = (floatx4){0.f, 0.f, 0.f, 0.f};
      qe[f] = MFMA(qa0, eb0, qe[f]);
      qe[f] = MFMA(qa1, eb1, qe[f]);
    }
    // ---- deferred PV + l for step kt-1 (V(s-1) retired at step top;
    //      independent of QK/QE/skew -> fills their latency shadow) ----
    if (kt > klo) {
#pragma unroll
      for (int nb = 0; nb < 4; ++nb) {
        short8 v0 = *(const short8*)&sVT[vprev][16 * nb + n_][c0s];
        short8 v1 = *(const short8*)&sVT[vprev][16 * nb + n_][c1s];
        ctxa[nb] = MFMA(pa0p, v0, ctxa[nb]);
        ctxa[nb] = MFMA(pa1p, v1, ctxa[nb]);
      }
      lacc = MFMA(pa0p, onesf, lacc);
      lacc = MFMA(pa1p, onesf, lacc);
    }
    __builtin_amdgcn_s_setprio(0);

    // ---- skew diagonal (16 bpermute, source-side frag select) + exp + sP --
    const bool diag = (kt == ti);
#pragma unroll
    for (int r = 0; r < 4; ++r) {
      const int t = 4 * q_ + r;
      const int ba = ((q_ << 4) | ((n_ - t + 15) & 15)) << 2;
      const int nd = (n_ + t + 1) & 15;   // dest lane (same q_) pulling from us
      const bool hi = nd > t;             // dest picks qe[mb+1] iff its n_ > t
      const int swr = (t & 7) << 3;       // sP row-swizzle term
#pragma unroll
      for (int mb = 0; mb < 4; ++mb) {
        float merged = hi ? qe[mb + 1][r] : qe[mb][r];
        float g = __int_as_float(
            __builtin_amdgcn_ds_bpermute(ba, __float_as_int(merged)));
        float sv = qk[mb][r] + g;
        if (diag && (16 * mb + n_ > 16 * w + t)) sv = -1.0e30f;  // exp -> 0
        // exp(sv*0.125) == exp2(sv * 0.125*log2(e))
        sP[16 * w + t][(16 * mb + n_) ^ swr] =
            (short)f2bf(exp2f(sv * 0.18033688011f));
      }
    }

    // ---- read own P strip into regs for NEXT step's deferred PV ----
    pa0p = *(const short8*)&sP[16 * w + n_][c0s];
    pa1p = *(const short8*)&sP[16 * w + n_][c1s];

    // Advance ring counters.
    vcur = vnext;
    slotA = slotB;
    slotB = slotC;
  }
#undef STAGE_K
#undef STAGE_E
#undef STAGE_V

  // ---- epilogue: V(khi-1) fully retired, then last PV + l ----
  asm volatile("s_waitcnt vmcnt(0)" ::: "memory");
  __builtin_amdgcn_sched_barrier(0);
  __builtin_amdgcn_s_barrier();
  __builtin_amdgcn_sched_barrier(0);
  {
    const int vlast = vcur == 0 ? 2 : vcur - 1;  // slot of step khi-1
    __builtin_amdgcn_s_setprio(1);
#pragma unroll
    for (int nb = 0; nb < 4; ++nb) {
      short8 v0 = *(const short8*)&sVT[vlast][16 * nb + n_][c0s];
      short8 v1 = *(const short8*)&sVT[vlast][16 * nb + n_][c1s];
      ctxa[nb] = MFMA(pa0p, v0, ctxa[nb]);
      ctxa[nb] = MFMA(pa1p, v1, ctxa[nb]);
    }
    lacc = MFMA(pa0p, onesf, lacc);
    lacc = MFMA(pa1p, onesf, lacc);
    __builtin_amdgcn_s_setprio(0);
  }

  if (nc == 1) {
#pragma unroll
    for (int r = 0; r < 4; ++r) {
      const float inv = 1.0f / lacc[r];
      const int row = t0 + 16 * w + 4 * q_ + r;
      const size_t base = (((size_t)((b << 11) + row)) << 9) + (h << 6) + n_;
#pragma unroll
      for (int nb = 0; nb < 4; ++nb)
        ctxo[base + 16 * nb] = f2bf(ctxa[nb][r] * inv);
    }
  } else {
    const int idx = hb * 72 + pbase_of(ti) + c;
    float* pcb = pc + ((size_t)idx << 12);   // *4096
    float* mlb = ml + ((size_t)idx << 6);    // *64
#pragma unroll
    for (int r = 0; r < 4; ++r) {
      const int row = 16 * w + 4 * q_ + r;
#pragma unroll
      for (int nb = 0; nb < 4; ++nb)
        pcb[(row << 6) + 16 * nb + n_] = ctxa[nb][r];
      if (n_ == 0) mlb[row] = lacc[r];
    }
  }
}

// ---------------------------------------------------------------------------
// K2b: combine chunk partials: out = sum(c_i) / sum(l_i). grid 384 blocks
// (16 hb x 24 multi-chunk tiles, ti 8..31).
// ---------------------------------------------------------------------------
__global__ __launch_bounds__(256) void combine_kernel(
    const float* __restrict__ pc, const float* __restrict__ ml,
    unsigned short* __restrict__ ctxo) {
  const int cb = blockIdx.x;
  const int hb = cb / 24;
  const int ti = 8 + cb % 24;
  const int nc = (ti >> 3) + 1;
  const int h = hb >> 1, b = hb & 1, t0 = ti * 64;
  const int tid = threadIdx.x;
  const int row = tid >> 2, seg = (tid & 3) * 16;
  const int idx0 = hb * 72 + pbase_of(ti);

  float lsum = 0.f;
  float4 a4[4];
#pragma unroll
  for (int j = 0; j < 4; ++j) a4[j] = (float4){0.f, 0.f, 0.f, 0.f};
  for (int c = 0; c < nc; ++c) {
    const int idx = idx0 + c;
    lsum += ml[((size_t)idx << 6) + row];
    const float* cp = pc + ((size_t)idx << 12) + (row << 6) + seg;
#pragma unroll
    for (int j = 0; j < 4; ++j) {
      float4 x = *(const float4*)(cp + 4 * j);
      a4[j].x += x.x; a4[j].y += x.y; a4[j].z += x.z; a4[j].w += x.w;
    }
  }
  const float inv = 1.0f / lsum;
  unsigned short o[16];
#pragma unroll
  for (int j = 0; j < 4; ++j) {
    o[4 * j + 0] = f2bf(a4[j].x * inv);
    o[4 * j + 1] = f2bf(a4[j].y * inv);
    o[4 * j + 2] = f2bf(a4[j].z * inv);
    o[4 * j + 3] = f2bf(a4[j].w * inv);
  }
  unsigned short* dst =
      ctxo + (((size_t)((b << 11) + t0 + row)) << 9) + (h << 6) + seg;
  *(uint4*)dst = *(uint4*)&o[0];
  *(uint4*)(dst + 8) = *(uint4*)&o[8];
}

// ---------------------------------------------------------------------------
// K3 (R18): MFMA GEMM with DMA staging. A bf16 [4096][512] @ WT bf16
// [Npad][512] + bias, tile 64x64, K-steps of 64, double-buffered swizzled
// LDS filled by global_load_lds (pre-swizzled source), ONE s_barrier +
// vmcnt(0) per step. RELU=1: out h1 bf16 [4096][512]. RELU=0: out d_out
// (dtype per mask), N=388 (WlT has 448 rows; max row read = 447).
// ---------------------------------------------------------------------------
template <int RELU>
__global__ __launch_bounds__(256) void mlp_mfma(
    const unsigned short* __restrict__ A, const unsigned short* __restrict__ WT,
    const void* __restrict__ bias, unsigned short* __restrict__ outBF,
    void* __restrict__ outD, const unsigned int* __restrict__ mask) {
  __shared__ __align__(16) short sA[2][64][64];   // 16 KB
  __shared__ __align__(16) short sW[2][64][64];   // 16 KB
  const int tid = threadIdx.x;
  const int w = tid >> 6, lane = tid & 63;
  const int q_ = lane >> 4, n_ = lane & 15;
  const int row0 = blockIdx.x * 64;
  const int n0 = blockIdx.y * 64;
  const bool isbf = det_bf(mask);

  const int lrow8 = lane >> 3;                     // 0..7
  const int lch = ((lane & 7) ^ lrow8) << 3;       // swizzled source col
  const int c0s = ((q_ ^ (n_ & 7)) << 3);
  const int c1s = (((q_ | 4) ^ (n_ & 7)) << 3);

#define MSTAGE(buf, k0v)                                                       \
  {                                                                            \
    const unsigned short* gA =                                                 \
        A + (size_t)(row0 + 16 * w + lrow8) * DM_ + (k0v) + lch;               \
    const unsigned short* gW =                                                 \
        WT + (size_t)(n0 + 16 * w + lrow8) * DM_ + (k0v) + lch;                \
    gl_lds16(gA, (void*)&sA[buf][16 * w][0]);                                  \
    gl_lds16(gA + 8 * DM_, (void*)(&sA[buf][16 * w][0] + 8 * 64));             \
    gl_lds16(gW, (void*)&sW[buf][16 * w][0]);                                  \
    gl_lds16(gW + 8 * DM_, (void*)(&sW[buf][16 * w][0] + 8 * 64));             \
  }

  floatx4 acc[4];
#pragma unroll
  for (int j = 0; j < 4; ++j) acc[j] = (floatx4){0.f, 0.f, 0.f, 0.f};

  MSTAGE(0, 0);
  for (int ks = 0; ks < DM_ / 64; ++ks) {
    const int buf = ks & 1;
    asm volatile("s_waitcnt vmcnt(0)" ::: "memory");
    __builtin_amdgcn_sched_barrier(0);
    __builtin_amdgcn_s_barrier();
    __builtin_amdgcn_sched_barrier(0);
    if (ks + 1 < DM_ / 64) MSTAGE(buf ^ 1, (ks + 1) * 64);

    short8 a0 = *(const short8*)&sA[buf][16 * w + n_][c0s];
    short8 a1 = *(const short8*)&sA[buf][16 * w + n_][c1s];
    __builtin_amdgcn_s_setprio(1);
#pragma unroll
    for (int nb = 0; nb < 4; ++nb) {
      short8 b0 = *(const short8*)&sW[buf][16 * nb + n_][c0s];
      short8 b1 = *(const short8*)&sW[buf][16 * nb + n_][c1s];
      acc[nb] = MFMA(a0, b0, acc[nb]);
      acc[nb] = MFMA(a1, b1, acc[nb]);
    }
    __builtin_amdgcn_s_setprio(0);
  }
#undef MSTAGE

#pragma unroll
  for (int nb = 0; nb < 4; ++nb) {
    const int col = n0 + 16 * nb + n_;
    float bb = 0.f;
    if (RELU || col < EV_) bb = ldf(bias, col, isbf);
#pragma unroll
    for (int r = 0; r < 4; ++r) {
      const int row = row0 + 16 * w + 4 * q_ + r;
      float v = acc[nb][r] + bb;
      if (RELU) {
        outBF[(size_t)row * ED_ + col] = f2bf(fmaxf(v, 0.f));
      } else if (col < EV_) {
        if (isbf) ((unsigned short*)outD)[(size_t)row * EV_ + col] = f2bf(v);
        else      ((float*)outD)[(size_t)row * EV_ + col] = v;
      }
    }
  }
}

// ---------------------------------------------------------------------------
extern "C" void kernel_launch(void* const* d_in, const int* in_sizes, int n_in,
                              void* d_out, int out_size, void* d_ws, size_t ws_size,
                              hipStream_t stream) {
  const void* v  = d_in[0];
  const void* k  = d_in[1];
  const void* q  = d_in[2];
  const unsigned int* mask = (const unsigned int*)d_in[3];
  const void* Wq = d_in[4];
  const void* bq = d_in[5];
  const void* Wk = d_in[6];
  const void* bk = d_in[7];
  const void* Wv = d_in[8];
  const void* bv = d_in[9];
  const void* E  = d_in[10];
  const void* Wo = d_in[11];
  const void* bo = d_in[12];
  const void* Wl = d_in[13];
  const void* bl = d_in[14];

  char* p = (char*)d_ws;
  unsigned short* E_c  = (unsigned short*)p; p += (size_t)H_ * T_ * HD_ * 2;  // 2 MB
  unsigned short* qhb  = (unsigned short*)p; p += (size_t)BT_ * HD_ * 2;
  unsigned short* khb  = (unsigned short*)p; p += (size_t)BT_ * HD_ * 2;
  unsigned short* vtb  = (unsigned short*)p; p += (size_t)BT_ * HD_ * 2;
  unsigned short* WqT  = (unsigned short*)p; p += (size_t)HD_ * DM_ * 2;
  unsigned short* WkT  = (unsigned short*)p; p += (size_t)HD_ * DM_ * 2;
  unsigned short* WvT  = (unsigned short*)p; p += (size_t)HD_ * DM_ * 2;
  unsigned short* WoT  = (unsigned short*)p; p += (size_t)ED_ * DM_ * 2;
  unsigned short* WlT  = (unsigned short*)p; p += (size_t)448 * DM_ * 2;
  unsigned short* ctxb = (unsigned short*)p; p += (size_t)BT_ * DM_ * 2;      // 4 MB
  unsigned short* h1b  = (unsigned short*)p; p += (size_t)BT_ * ED_ * 2;      // 4 MB
  float* pc = (float*)p; p += (size_t)16 * 72 * 4096 * 4;                     // 18.9 MB
  float* ml = (float*)p; p += (size_t)16 * 72 * 64 * 4;                       // 0.3 MB

  prep_kernel<<<dim3(1312), 256, 0, stream>>>(
      E, Wq, Wk, Wv, Wo, Wl, mask, E_c, WqT, WkT, WvT, WoT, WlT);
  gemm_proj<<<dim3(BT_ / 64, 3), 256, 0, stream>>>(
      q, k, v, WqT, WkT, WvT, bq, bk, bv, mask, qhb, khb, vtb);
  attn_kernel<<<dim3(1280), 256, 0, stream>>>(qhb, khb, vtb, E_c, ctxb, pc, ml);
  combine_kernel<<<dim3(384), 256, 0, stream>>>(pc, ml, ctxb);
  mlp_mfma<1><<<dim3(BT_ / 64, ED_ / 64), 256, 0, stream>>>(
      ctxb, WoT, bo, h1b, nullptr, mask);
  mlp_mfma<0><<<dim3(BT_ / 64, 448 / 64), 256, 0, stream>>>(
      h1b, WlT, bl, nullptr, d_out, mask);
}